// Round 7
// baseline (587.934 us; speedup 1.0000x reference)
//
#include <hip/hip_runtime.h>

#define N_PY 512
#define IN_F 6
#define OUT_F 64
#define N_CELLS (512 * 512)
#define NB 1024                   // buckets: cell >> 8  (256 cells per bucket)
#define CHUNK 4096                // points per bin-staging block
#define BN_EPS 1e-5

// ---------------------------------------------------------------------------
// ws layout (binned path):
//   [0, 108)        : 27 floats — moment accumulators
//   [512, 2048)     : float Wp[64*6], float bp[64] — BN-folded params
//   [4096, 8192)    : int hist[1024]   — per-bucket point count
//   [8192, 12292)   : int S[1025]      — exclusive scan (S[1024]=n)
//   [12800, 16896)  : int cursor[1024] — mutable copy of scan for binning
//   [16896, +32*n)  : float rec[n*8]   — 32B records {x0..x5, cell, pad}
// fallback (linked-list) reuses [4096...) as head[N_CELLS] + nxt[n].
// ---------------------------------------------------------------------------

__global__ void __launch_bounds__(256)
pfn_stats_hist_kernel(const float* __restrict__ x, const int* __restrict__ idx,
                      int n, float* __restrict__ acc, int* __restrict__ hist) {
    const int tid = blockIdx.x * blockDim.x + threadIdx.x;
    const int stride = gridDim.x * blockDim.x;
    const int npairs = n >> 1;

    float s[27];
#pragma unroll
    for (int k = 0; k < 27; ++k) s[k] = 0.f;

    for (int q = tid; q < npairs; q += stride) {
        const float4* base4 = (const float4*)(x + (size_t)q * 12);
        const float4 a = base4[0];
        const float4 b4 = base4[1];
        const float4 c4 = base4[2];
        const float p0[6] = {a.x, a.y, a.z, a.w, b4.x, b4.y};
        const float p1[6] = {b4.z, b4.w, c4.x, c4.y, c4.z, c4.w};
#pragma unroll
        for (int j = 0; j < 6; ++j) s[j] += p0[j] + p1[j];
        int k = 6;
#pragma unroll
        for (int i = 0; i < 6; ++i)
#pragma unroll
            for (int j = i; j < 6; ++j) {
                s[k] += p0[i] * p0[j] + p1[i] * p1[j];
                ++k;
            }
    }
    if ((n & 1) && tid == 0) {
        const float* p = x + (size_t)(n - 1) * 6;
        float v[6];
#pragma unroll
        for (int j = 0; j < 6; ++j) v[j] = p[j];
#pragma unroll
        for (int j = 0; j < 6; ++j) s[j] += v[j];
        int k = 6;
#pragma unroll
        for (int i = 0; i < 6; ++i)
#pragma unroll
            for (int j = i; j < 6; ++j) { s[k] += v[i] * v[j]; ++k; }
    }

    // bucket histogram: 2 points per int4, fire-and-forget atomics on 4KB array
    for (int q = tid; q < npairs; q += stride) {
        const int4 ij2 = ((const int4*)idx)[q];
        atomicAdd(&hist[(ij2.x * N_PY + ij2.y) >> 8], 1);
        atomicAdd(&hist[(ij2.z * N_PY + ij2.w) >> 8], 1);
    }
    if ((n & 1) && tid == 0) {
        const int2 ij = ((const int2*)idx)[n - 1];
        atomicAdd(&hist[(ij.x * N_PY + ij.y) >> 8], 1);
    }

#pragma unroll
    for (int off = 32; off > 0; off >>= 1)
#pragma unroll
        for (int k = 0; k < 27; ++k) s[k] += __shfl_down(s[k], off, 64);

    __shared__ float lds[4][27];
    const int wid = threadIdx.x >> 6;
    const int lane = threadIdx.x & 63;
    if (lane == 0)
#pragma unroll
        for (int k = 0; k < 27; ++k) lds[wid][k] = s[k];
    __syncthreads();

    if (threadIdx.x < 27) {
        const int k = threadIdx.x;
        const float v = lds[0][k] + lds[1][k] + lds[2][k] + lds[3][k];
        atomicAdd(&acc[k], v);
    }
}

// single block, 256 threads: exclusive scan of hist[1024] -> S[], cursor[],
// plus BN-param fold on threads 0..63.
__global__ void __launch_bounds__(256)
pfn_scan_finalize_kernel(const int* __restrict__ hist,
                         int* __restrict__ S, int* __restrict__ cursor, int n,
                         const float* __restrict__ acc,
                         const float* __restrict__ W,
                         const float* __restrict__ b,
                         const float* __restrict__ gamma,
                         const float* __restrict__ beta,
                         float* __restrict__ Wp, float* __restrict__ bp) {
    const int tid = threadIdx.x;   // 256 threads x 4 entries = 1024
    const int4 q = ((const int4*)hist)[tid];
    int v[4] = {q.x, q.y, q.z, q.w};
    int pre[4];
    int tot = 0;
#pragma unroll
    for (int k = 0; k < 4; ++k) { pre[k] = tot; tot += v[k]; }

    __shared__ int sc[256];
    sc[tid] = tot;
    __syncthreads();
#pragma unroll
    for (int off = 1; off < 256; off <<= 1) {
        const int add = (tid >= off) ? sc[tid - off] : 0;
        __syncthreads();
        sc[tid] += add;
        __syncthreads();
    }
    const int excl = sc[tid] - tot;
#pragma unroll
    for (int k = 0; k < 4; ++k) {
        const int val = excl + pre[k];
        S[tid * 4 + k] = val;
        cursor[tid * 4 + k] = val;
    }
    if (tid == 255) S[NB] = n;

    // ---- BN-fold ----
    if (tid < 64) {
        const int f = tid;
        double inv_n = 1.0 / (double)n;
        double mx[6];
#pragma unroll
        for (int j = 0; j < 6; ++j) mx[j] = (double)acc[j] * inv_n;
        double C[6][6];
        {
            int k = 0;
            for (int i = 0; i < 6; ++i)
                for (int j = i; j < 6; ++j) {
                    double e = (double)acc[6 + k] * inv_n - mx[i] * mx[j];
                    C[i][j] = e; C[j][i] = e; ++k;
                }
        }
        double w[6];
#pragma unroll
        for (int j = 0; j < 6; ++j) w[j] = (double)W[f * 6 + j];
        double mean_h = (double)b[f];
#pragma unroll
        for (int j = 0; j < 6; ++j) mean_h += w[j] * mx[j];
        double var_h = 0.0;
        for (int i = 0; i < 6; ++i) {
            double t = 0.0;
            for (int j = 0; j < 6; ++j) t += C[i][j] * w[j];
            var_h += w[i] * t;
        }
        double sgn = (double)gamma[f] / sqrt(var_h + BN_EPS);
#pragma unroll
        for (int j = 0; j < 6; ++j) Wp[f * 6 + j] = (float)(w[j] * sgn);
        bp[f] = (float)(((double)b[f] - mean_h) * sgn + (double)beta[f]);
    }
}

// LDS-staged partition: each block owns a 4096-point chunk. Local histogram ->
// local scan -> reserve global ranges -> rank points -> write records in
// bucket order (runs of ~4 records = 128B contiguous, sector-friendly).
__global__ void __launch_bounds__(256)
pfn_bin_staged_kernel(const float* __restrict__ x, const int* __restrict__ idx,
                      int* __restrict__ gcursor, float* __restrict__ rec, int n) {
    __shared__ int lhist[NB];     // 4KB
    __shared__ int lbase[NB];     // 4KB
    __shared__ int lcur[NB];      // 4KB
    __shared__ int gbase[NB];     // 4KB
    __shared__ int spid[CHUNK];   // 16KB — staged point id per slot
    __shared__ int scell[CHUNK];  // 16KB — staged cell per slot
    __shared__ int sc[256];       // 1KB

    const int tid = threadIdx.x;
    const int chunkStart = blockIdx.x * CHUNK;
    const int chunkCount = min(CHUNK, n - chunkStart);

    // phase 0: zero local hist
#pragma unroll
    for (int k = 0; k < 4; ++k) lhist[tid * 4 + k] = 0;
    __syncthreads();

    // phase 1: local histogram; keep cells in registers
    int cellr[16];
#pragma unroll
    for (int r = 0; r < 16; ++r) {
        const int i = r * 256 + tid;
        cellr[r] = -1;
        if (i < chunkCount) {
            const int2 ij = ((const int2*)idx)[chunkStart + i];
            const int cell = ij.x * N_PY + ij.y;
            cellr[r] = cell;
            atomicAdd(&lhist[cell >> 8], 1);
        }
    }
    __syncthreads();

    // phase 2: exclusive scan of lhist (4 entries/thread) + reserve global ranges
    int v[4], pre[4];
    int tot = 0;
#pragma unroll
    for (int k = 0; k < 4; ++k) {
        v[k] = lhist[tid * 4 + k];
        pre[k] = tot;
        tot += v[k];
    }
    sc[tid] = tot;
    __syncthreads();
#pragma unroll
    for (int off = 1; off < 256; off <<= 1) {
        const int add = (tid >= off) ? sc[tid - off] : 0;
        __syncthreads();
        sc[tid] += add;
        __syncthreads();
    }
    const int excl = sc[tid] - tot;
#pragma unroll
    for (int k = 0; k < 4; ++k) {
        const int bkt = tid * 4 + k;
        const int base = excl + pre[k];
        lbase[bkt] = base;
        lcur[bkt] = base;
        gbase[bkt] = (v[k] > 0) ? atomicAdd(&gcursor[bkt], v[k]) : 0;
    }
    __syncthreads();

    // phase 3: rank each point -> staged slot (bucket-ordered)
#pragma unroll
    for (int r = 0; r < 16; ++r) {
        const int cell = cellr[r];
        if (cell >= 0) {
            const int slot = atomicAdd(&lcur[cell >> 8], 1);
            spid[slot] = chunkStart + r * 256 + tid;
            scell[slot] = cell;
        }
    }
    __syncthreads();

    // phase 4: write out in staged (bucket) order -> coalesced global runs.
    // x rows gathered from the block's own contiguous chunk (L2-hot).
#pragma unroll
    for (int r = 0; r < 16; ++r) {
        const int slot = r * 256 + tid;
        if (slot < chunkCount) {
            const int p = spid[slot];
            const int cell = scell[slot];
            const int bkt = cell >> 8;
            const int pos = gbase[bkt] + (slot - lbase[bkt]);
            const float2* xp = (const float2*)(x + (size_t)p * 6);
            const float2 a = xp[0], b2 = xp[1], c = xp[2];
            float4* d = (float4*)(rec + (size_t)pos * 8);
            d[0] = float4{a.x, a.y, b2.x, b2.y};
            d[1] = float4{c.x, c.y, __int_as_float(cell), 0.f};
        }
    }
}

// one block per 256-cell bucket: 64KB LDS tile, LDS f32 atomics (ds_add),
// 4 waves split the segment into quarters, unroll-4 (8 loads in flight),
// coalesced 64KB flush. Output written exactly once -> no d_out memset.
__global__ void __launch_bounds__(256)
pfn_tile_kernel(const float* __restrict__ rec, const int* __restrict__ S,
                const float* __restrict__ Wp, const float* __restrict__ bp,
                float* __restrict__ out) {
    __shared__ float tile[256 * OUT_F];   // 64 KB
    const int tid = threadIdx.x;
    const int lane = tid & 63;
    const int wid = tid >> 6;
    const int bucket = blockIdx.x;

    float4* t4 = (float4*)tile;
#pragma unroll
    for (int i = 0; i < 16; ++i)
        t4[tid + 256 * i] = float4{0.f, 0.f, 0.f, 0.f};

    const float w0 = Wp[lane * 6 + 0];
    const float w1 = Wp[lane * 6 + 1];
    const float w2 = Wp[lane * 6 + 2];
    const float w3 = Wp[lane * 6 + 3];
    const float w4 = Wp[lane * 6 + 4];
    const float w5 = Wp[lane * 6 + 5];
    const float bb = bp[lane];

    __syncthreads();

    const int r0 = S[bucket];
    const int r1 = S[bucket + 1];
    const int cnt = r1 - r0;
    int r = r0 + (cnt * wid) / 4;          // this wave's quarter
    const int re = r0 + (cnt * (wid + 1)) / 4;

    for (; r + 4 <= re; r += 4) {
        const float4* q0 = (const float4*)(rec + (size_t)(r + 0) * 8);
        const float4* q1 = (const float4*)(rec + (size_t)(r + 1) * 8);
        const float4* q2 = (const float4*)(rec + (size_t)(r + 2) * 8);
        const float4* q3 = (const float4*)(rec + (size_t)(r + 3) * 8);
        const float4 a0 = q0[0], a1 = q0[1];
        const float4 b0 = q1[0], b1 = q1[1];
        const float4 c0 = q2[0], c1 = q2[1];
        const float4 d0 = q3[0], d1 = q3[1];

        float v;
        v = bb;
        v = fmaf(w0, a0.x, v); v = fmaf(w1, a0.y, v); v = fmaf(w2, a0.z, v);
        v = fmaf(w3, a0.w, v); v = fmaf(w4, a1.x, v); v = fmaf(w5, a1.y, v);
        atomicAdd(&tile[((__float_as_int(a1.z) & 255) << 6) | lane], fmaxf(v, 0.f));

        v = bb;
        v = fmaf(w0, b0.x, v); v = fmaf(w1, b0.y, v); v = fmaf(w2, b0.z, v);
        v = fmaf(w3, b0.w, v); v = fmaf(w4, b1.x, v); v = fmaf(w5, b1.y, v);
        atomicAdd(&tile[((__float_as_int(b1.z) & 255) << 6) | lane], fmaxf(v, 0.f));

        v = bb;
        v = fmaf(w0, c0.x, v); v = fmaf(w1, c0.y, v); v = fmaf(w2, c0.z, v);
        v = fmaf(w3, c0.w, v); v = fmaf(w4, c1.x, v); v = fmaf(w5, c1.y, v);
        atomicAdd(&tile[((__float_as_int(c1.z) & 255) << 6) | lane], fmaxf(v, 0.f));

        v = bb;
        v = fmaf(w0, d0.x, v); v = fmaf(w1, d0.y, v); v = fmaf(w2, d0.z, v);
        v = fmaf(w3, d0.w, v); v = fmaf(w4, d1.x, v); v = fmaf(w5, d1.y, v);
        atomicAdd(&tile[((__float_as_int(d1.z) & 255) << 6) | lane], fmaxf(v, 0.f));
    }
    for (; r < re; ++r) {
        const float4* q = (const float4*)(rec + (size_t)r * 8);
        const float4 A0 = q[0], A1 = q[1];
        float v = bb;
        v = fmaf(w0, A0.x, v); v = fmaf(w1, A0.y, v); v = fmaf(w2, A0.z, v);
        v = fmaf(w3, A0.w, v); v = fmaf(w4, A1.x, v); v = fmaf(w5, A1.y, v);
        atomicAdd(&tile[((__float_as_int(A1.z) & 255) << 6) | lane], fmaxf(v, 0.f));
    }
    __syncthreads();

    float4* o4 = (float4*)(out + (size_t)bucket * (256 * OUT_F));
#pragma unroll
    for (int i = 0; i < 16; ++i)
        o4[tid + 256 * i] = t4[tid + 256 * i];
}

// ---- fallback (linked-list path, small ws) ----
__global__ void __launch_bounds__(256)
pfn_build_kernel(const int* __restrict__ idx, int n,
                 int* __restrict__ head, int* __restrict__ nxt) {
    const int p = blockIdx.x * blockDim.x + threadIdx.x;
    if (p >= n) return;
    const int2 ij = ((const int2*)idx)[p];
    const int cell = ij.x * N_PY + ij.y;
    nxt[p] = atomicExch(&head[cell], p);
}

__global__ void pfn_finalize_kernel(const float* __restrict__ acc,
                                    const float* __restrict__ W,
                                    const float* __restrict__ b,
                                    const float* __restrict__ gamma,
                                    const float* __restrict__ beta,
                                    int n,
                                    float* __restrict__ Wp,
                                    float* __restrict__ bp) {
    int f = threadIdx.x;
    double inv_n = 1.0 / (double)n;
    double mx[6];
#pragma unroll
    for (int j = 0; j < 6; ++j) mx[j] = (double)acc[j] * inv_n;
    double C[6][6];
    {
        int k = 0;
        for (int i = 0; i < 6; ++i)
            for (int j = i; j < 6; ++j) {
                double e = (double)acc[6 + k] * inv_n - mx[i] * mx[j];
                C[i][j] = e; C[j][i] = e; ++k;
            }
    }
    double w[6];
#pragma unroll
    for (int j = 0; j < 6; ++j) w[j] = (double)W[f * 6 + j];
    double mean_h = (double)b[f];
#pragma unroll
    for (int j = 0; j < 6; ++j) mean_h += w[j] * mx[j];
    double var_h = 0.0;
    for (int i = 0; i < 6; ++i) {
        double t = 0.0;
        for (int j = 0; j < 6; ++j) t += C[i][j] * w[j];
        var_h += w[i] * t;
    }
    double s = (double)gamma[f] / sqrt(var_h + BN_EPS);
#pragma unroll
    for (int j = 0; j < 6; ++j) Wp[f * 6 + j] = (float)(w[j] * s);
    bp[f] = (float)(((double)b[f] - mean_h) * s + (double)beta[f]);
}

__global__ void __launch_bounds__(256)
pfn_output_kernel(const float* __restrict__ x,
                  const int* __restrict__ head,
                  const int* __restrict__ nxt,
                  const float* __restrict__ Wp,
                  const float* __restrict__ bp,
                  float* __restrict__ out) {
    const int lane = threadIdx.x & 63;
    const int cell = __builtin_amdgcn_readfirstlane(
        (int)((blockIdx.x * blockDim.x + threadIdx.x) >> 6));

    const float w0 = Wp[lane * 6 + 0];
    const float w1 = Wp[lane * 6 + 1];
    const float w2 = Wp[lane * 6 + 2];
    const float w3 = Wp[lane * 6 + 3];
    const float w4 = Wp[lane * 6 + 4];
    const float w5 = Wp[lane * 6 + 5];
    const float bb = bp[lane];

    float s = 0.f;
    int p = head[cell];
    while (p >= 0) {
        const float* xp = x + (size_t)p * 6;
        const int pn = nxt[p];
        float v = bb;
        v = fmaf(w0, xp[0], v);
        v = fmaf(w1, xp[1], v);
        v = fmaf(w2, xp[2], v);
        v = fmaf(w3, xp[3], v);
        v = fmaf(w4, xp[4], v);
        v = fmaf(w5, xp[5], v);
        s += fmaxf(v, 0.0f);
        p = pn;
    }
    out[(size_t)cell * OUT_F + lane] = s;
}

extern "C" void kernel_launch(void* const* d_in, const int* in_sizes, int n_in,
                              void* d_out, int out_size, void* d_ws, size_t ws_size,
                              hipStream_t stream) {
    const float* x     = (const float*)d_in[0];
    const int*   idx   = (const int*)d_in[1];
    const float* W     = (const float*)d_in[2];
    const float* b     = (const float*)d_in[3];
    const float* gamma = (const float*)d_in[4];
    const float* beta  = (const float*)d_in[5];
    float* out = (float*)d_out;

    const int n = in_sizes[0] / IN_F;

    float* acc = (float*)d_ws;
    float* Wp  = (float*)((char*)d_ws + 512);
    float* bp  = Wp + OUT_F * IN_F;

    int*   hist   = (int*)((char*)d_ws + 4096);    // 1024 ints
    int*   S      = (int*)((char*)d_ws + 8192);    // 1025 ints
    int*   cursor = (int*)((char*)d_ws + 12800);   // 1024 ints
    float* rec    = (float*)((char*)d_ws + 16896); // n * 8 floats, 32B recs

    const size_t need = 16896 + (size_t)n * 32;

    if (ws_size >= need) {
        // zero acc + hist (S/cursor fully written by scan kernel)
        hipMemsetAsync(d_ws, 0, 8192, stream);
        pfn_stats_hist_kernel<<<512, 256, 0, stream>>>(x, idx, n, acc, hist);
        pfn_scan_finalize_kernel<<<1, 256, 0, stream>>>(
            hist, S, cursor, n, acc, W, b, gamma, beta, Wp, bp);
        pfn_bin_staged_kernel<<<(n + CHUNK - 1) / CHUNK, 256, 0, stream>>>(
            x, idx, cursor, rec, n);
        pfn_tile_kernel<<<NB, 256, 0, stream>>>(rec, S, Wp, bp, out);
    } else {
        // linked-list fallback
        int* head = (int*)((char*)d_ws + 4096);
        int* nxt  = head + N_CELLS;
        hipMemsetAsync(d_ws, 0, 512, stream);
        pfn_stats_hist_kernel<<<512, 256, 0, stream>>>(x, idx, n, acc, head);
        hipMemsetAsync(head, 0xFF, (size_t)N_CELLS * sizeof(int), stream);
        pfn_finalize_kernel<<<1, 64, 0, stream>>>(acc, W, b, gamma, beta, n, Wp, bp);
        pfn_build_kernel<<<(n + 255) / 256, 256, 0, stream>>>(idx, n, head, nxt);
        pfn_output_kernel<<<N_CELLS / 4, 256, 0, stream>>>(x, head, nxt, Wp, bp, out);
    }
}

// Round 8
// 552.459 us; speedup vs baseline: 1.0642x; 1.0642x over previous
//
#include <hip/hip_runtime.h>

#define N_PY 512
#define IN_F 6
#define OUT_F 64
#define N_CELLS (512 * 512)
#define NB 1024                   // buckets: cell >> 8  (256 cells per bucket)
#define CHUNK 4096                // points per bin-staging block
#define BN_EPS 1e-5

// ---------------------------------------------------------------------------
// ws layout (binned path):
//   [0, 108)        : 27 floats — moment accumulators
//   [512, 2048)     : float Wp[64*6], float bp[64] — BN-folded params
//   [4096, 8192)    : int hist[1024]   — per-bucket point count
//   [8192, 12292)   : int S[1025]      — exclusive scan (S[1024]=n)
//   [12800, 16896)  : int cursor[1024] — mutable copy of scan for binning
//   [16896, +32*n)  : float rec[n*8]   — 32B records {x0..x5, cell, pad}
// fallback (linked-list) reuses [4096...) as head[N_CELLS] + nxt[n].
// ---------------------------------------------------------------------------

__global__ void __launch_bounds__(256)
pfn_stats_hist_kernel(const float* __restrict__ x, const int* __restrict__ idx,
                      int n, float* __restrict__ acc, int* __restrict__ hist) {
    const int tid = blockIdx.x * blockDim.x + threadIdx.x;
    const int stride = gridDim.x * blockDim.x;
    const int npairs = n >> 1;

    float s[27];
#pragma unroll
    for (int k = 0; k < 27; ++k) s[k] = 0.f;

    for (int q = tid; q < npairs; q += stride) {
        const float4* base4 = (const float4*)(x + (size_t)q * 12);
        const float4 a = base4[0];
        const float4 b4 = base4[1];
        const float4 c4 = base4[2];
        const float p0[6] = {a.x, a.y, a.z, a.w, b4.x, b4.y};
        const float p1[6] = {b4.z, b4.w, c4.x, c4.y, c4.z, c4.w};
#pragma unroll
        for (int j = 0; j < 6; ++j) s[j] += p0[j] + p1[j];
        int k = 6;
#pragma unroll
        for (int i = 0; i < 6; ++i)
#pragma unroll
            for (int j = i; j < 6; ++j) {
                s[k] += p0[i] * p0[j] + p1[i] * p1[j];
                ++k;
            }
    }
    if ((n & 1) && tid == 0) {
        const float* p = x + (size_t)(n - 1) * 6;
        float v[6];
#pragma unroll
        for (int j = 0; j < 6; ++j) v[j] = p[j];
#pragma unroll
        for (int j = 0; j < 6; ++j) s[j] += v[j];
        int k = 6;
#pragma unroll
        for (int i = 0; i < 6; ++i)
#pragma unroll
            for (int j = i; j < 6; ++j) { s[k] += v[i] * v[j]; ++k; }
    }

    // bucket histogram: 2 points per int4, fire-and-forget atomics on 4KB array
    for (int q = tid; q < npairs; q += stride) {
        const int4 ij2 = ((const int4*)idx)[q];
        atomicAdd(&hist[(ij2.x * N_PY + ij2.y) >> 8], 1);
        atomicAdd(&hist[(ij2.z * N_PY + ij2.w) >> 8], 1);
    }
    if ((n & 1) && tid == 0) {
        const int2 ij = ((const int2*)idx)[n - 1];
        atomicAdd(&hist[(ij.x * N_PY + ij.y) >> 8], 1);
    }

#pragma unroll
    for (int off = 32; off > 0; off >>= 1)
#pragma unroll
        for (int k = 0; k < 27; ++k) s[k] += __shfl_down(s[k], off, 64);

    __shared__ float lds[4][27];
    const int wid = threadIdx.x >> 6;
    const int lane = threadIdx.x & 63;
    if (lane == 0)
#pragma unroll
        for (int k = 0; k < 27; ++k) lds[wid][k] = s[k];
    __syncthreads();

    if (threadIdx.x < 27) {
        const int k = threadIdx.x;
        const float v = lds[0][k] + lds[1][k] + lds[2][k] + lds[3][k];
        atomicAdd(&acc[k], v);
    }
}

// single block, 256 threads: exclusive scan of hist[1024] -> S[], cursor[],
// plus BN-param fold on threads 0..63.
__global__ void __launch_bounds__(256)
pfn_scan_finalize_kernel(const int* __restrict__ hist,
                         int* __restrict__ S, int* __restrict__ cursor, int n,
                         const float* __restrict__ acc,
                         const float* __restrict__ W,
                         const float* __restrict__ b,
                         const float* __restrict__ gamma,
                         const float* __restrict__ beta,
                         float* __restrict__ Wp, float* __restrict__ bp) {
    const int tid = threadIdx.x;   // 256 threads x 4 entries = 1024
    const int4 q = ((const int4*)hist)[tid];
    int v[4] = {q.x, q.y, q.z, q.w};
    int pre[4];
    int tot = 0;
#pragma unroll
    for (int k = 0; k < 4; ++k) { pre[k] = tot; tot += v[k]; }

    __shared__ int sc[256];
    sc[tid] = tot;
    __syncthreads();
#pragma unroll
    for (int off = 1; off < 256; off <<= 1) {
        const int add = (tid >= off) ? sc[tid - off] : 0;
        __syncthreads();
        sc[tid] += add;
        __syncthreads();
    }
    const int excl = sc[tid] - tot;
#pragma unroll
    for (int k = 0; k < 4; ++k) {
        const int val = excl + pre[k];
        S[tid * 4 + k] = val;
        cursor[tid * 4 + k] = val;
    }
    if (tid == 255) S[NB] = n;

    // ---- BN-fold ----
    if (tid < 64) {
        const int f = tid;
        double inv_n = 1.0 / (double)n;
        double mx[6];
#pragma unroll
        for (int j = 0; j < 6; ++j) mx[j] = (double)acc[j] * inv_n;
        double C[6][6];
        {
            int k = 0;
            for (int i = 0; i < 6; ++i)
                for (int j = i; j < 6; ++j) {
                    double e = (double)acc[6 + k] * inv_n - mx[i] * mx[j];
                    C[i][j] = e; C[j][i] = e; ++k;
                }
        }
        double w[6];
#pragma unroll
        for (int j = 0; j < 6; ++j) w[j] = (double)W[f * 6 + j];
        double mean_h = (double)b[f];
#pragma unroll
        for (int j = 0; j < 6; ++j) mean_h += w[j] * mx[j];
        double var_h = 0.0;
        for (int i = 0; i < 6; ++i) {
            double t = 0.0;
            for (int j = 0; j < 6; ++j) t += C[i][j] * w[j];
            var_h += w[i] * t;
        }
        double sgn = (double)gamma[f] / sqrt(var_h + BN_EPS);
#pragma unroll
        for (int j = 0; j < 6; ++j) Wp[f * 6 + j] = (float)(w[j] * sgn);
        bp[f] = (float)(((double)b[f] - mean_h) * sgn + (double)beta[f]);
    }
}

// LDS-staged partition: each block owns a 4096-point chunk. Local histogram ->
// local scan -> reserve global ranges -> rank points -> write records in
// bucket order (runs of ~4 records = 128B contiguous, sector-friendly).
__global__ void __launch_bounds__(256)
pfn_bin_staged_kernel(const float* __restrict__ x, const int* __restrict__ idx,
                      int* __restrict__ gcursor, float* __restrict__ rec, int n) {
    __shared__ int lhist[NB];     // 4KB
    __shared__ int lbase[NB];     // 4KB
    __shared__ int lcur[NB];      // 4KB
    __shared__ int gbase[NB];     // 4KB
    __shared__ int spid[CHUNK];   // 16KB — staged point id per slot
    __shared__ int scell[CHUNK];  // 16KB — staged cell per slot
    __shared__ int sc[256];       // 1KB

    const int tid = threadIdx.x;
    const int chunkStart = blockIdx.x * CHUNK;
    const int chunkCount = min(CHUNK, n - chunkStart);

    // phase 0: zero local hist
#pragma unroll
    for (int k = 0; k < 4; ++k) lhist[tid * 4 + k] = 0;
    __syncthreads();

    // phase 1: local histogram; keep cells in registers
    int cellr[16];
#pragma unroll
    for (int r = 0; r < 16; ++r) {
        const int i = r * 256 + tid;
        cellr[r] = -1;
        if (i < chunkCount) {
            const int2 ij = ((const int2*)idx)[chunkStart + i];
            const int cell = ij.x * N_PY + ij.y;
            cellr[r] = cell;
            atomicAdd(&lhist[cell >> 8], 1);
        }
    }
    __syncthreads();

    // phase 2: exclusive scan of lhist (4 entries/thread) + reserve global ranges
    int v[4], pre[4];
    int tot = 0;
#pragma unroll
    for (int k = 0; k < 4; ++k) {
        v[k] = lhist[tid * 4 + k];
        pre[k] = tot;
        tot += v[k];
    }
    sc[tid] = tot;
    __syncthreads();
#pragma unroll
    for (int off = 1; off < 256; off <<= 1) {
        const int add = (tid >= off) ? sc[tid - off] : 0;
        __syncthreads();
        sc[tid] += add;
        __syncthreads();
    }
    const int excl = sc[tid] - tot;
#pragma unroll
    for (int k = 0; k < 4; ++k) {
        const int bkt = tid * 4 + k;
        const int base = excl + pre[k];
        lbase[bkt] = base;
        lcur[bkt] = base;
        gbase[bkt] = (v[k] > 0) ? atomicAdd(&gcursor[bkt], v[k]) : 0;
    }
    __syncthreads();

    // phase 3: rank each point -> staged slot (bucket-ordered)
#pragma unroll
    for (int r = 0; r < 16; ++r) {
        const int cell = cellr[r];
        if (cell >= 0) {
            const int slot = atomicAdd(&lcur[cell >> 8], 1);
            spid[slot] = chunkStart + r * 256 + tid;
            scell[slot] = cell;
        }
    }
    __syncthreads();

    // phase 4: write out in staged (bucket) order -> coalesced global runs.
    // x rows gathered from the block's own contiguous chunk (L2-hot).
#pragma unroll
    for (int r = 0; r < 16; ++r) {
        const int slot = r * 256 + tid;
        if (slot < chunkCount) {
            const int p = spid[slot];
            const int cell = scell[slot];
            const int bkt = cell >> 8;
            const int pos = gbase[bkt] + (slot - lbase[bkt]);
            const float2* xp = (const float2*)(x + (size_t)p * 6);
            const float2 a = xp[0], b2 = xp[1], c = xp[2];
            float4* d = (float4*)(rec + (size_t)pos * 8);
            d[0] = float4{a.x, a.y, b2.x, b2.y};
            d[1] = float4{c.x, c.y, __int_as_float(cell), 0.f};
        }
    }
}

// one block per 256-cell bucket: 64KB LDS tile, NO LDS atomics. Wave w owns
// the 64 cells with (cell>>6)&3 == w (its private 16KB quarter). Every wave
// scans the full record segment (broadcast loads, L1-shared across waves),
// accumulates only its own cells with plain += under a wave-uniform branch.
// Coalesced 64KB flush; output written exactly once -> no d_out memset.
__global__ void __launch_bounds__(256)
pfn_tile_kernel(const float* __restrict__ rec, const int* __restrict__ S,
                const float* __restrict__ Wp, const float* __restrict__ bp,
                float* __restrict__ out) {
    __shared__ float tile[256 * OUT_F];   // 64 KB
    const int tid = threadIdx.x;
    const int lane = tid & 63;
    const int wid = tid >> 6;
    const int bucket = blockIdx.x;

    float4* t4 = (float4*)tile;
#pragma unroll
    for (int i = 0; i < 16; ++i)
        t4[tid + 256 * i] = float4{0.f, 0.f, 0.f, 0.f};

    const float w0 = Wp[lane * 6 + 0];
    const float w1 = Wp[lane * 6 + 1];
    const float w2 = Wp[lane * 6 + 2];
    const float w3 = Wp[lane * 6 + 3];
    const float w4 = Wp[lane * 6 + 4];
    const float w5 = Wp[lane * 6 + 5];
    const float bb = bp[lane];

    __syncthreads();

    int r = S[bucket];
    const int r1 = S[bucket + 1];

    for (; r + 4 <= r1; r += 4) {
        const float4* q0 = (const float4*)(rec + (size_t)(r + 0) * 8);
        const float4* q1 = (const float4*)(rec + (size_t)(r + 1) * 8);
        const float4* q2 = (const float4*)(rec + (size_t)(r + 2) * 8);
        const float4* q3 = (const float4*)(rec + (size_t)(r + 3) * 8);
        const float4 a0 = q0[0], a1 = q0[1];
        const float4 b0 = q1[0], b1 = q1[1];
        const float4 c0 = q2[0], c1 = q2[1];
        const float4 d0 = q3[0], d1 = q3[1];

        const int cA = __float_as_int(a1.z);
        const int cB = __float_as_int(b1.z);
        const int cC = __float_as_int(c1.z);
        const int cD = __float_as_int(d1.z);

        float v;
        v = bb;
        v = fmaf(w0, a0.x, v); v = fmaf(w1, a0.y, v); v = fmaf(w2, a0.z, v);
        v = fmaf(w3, a0.w, v); v = fmaf(w4, a1.x, v); v = fmaf(w5, a1.y, v);
        if (((cA >> 6) & 3) == wid)                      // wave-uniform branch
            tile[((cA & 255) << 6) | lane] += fmaxf(v, 0.f);

        v = bb;
        v = fmaf(w0, b0.x, v); v = fmaf(w1, b0.y, v); v = fmaf(w2, b0.z, v);
        v = fmaf(w3, b0.w, v); v = fmaf(w4, b1.x, v); v = fmaf(w5, b1.y, v);
        if (((cB >> 6) & 3) == wid)
            tile[((cB & 255) << 6) | lane] += fmaxf(v, 0.f);

        v = bb;
        v = fmaf(w0, c0.x, v); v = fmaf(w1, c0.y, v); v = fmaf(w2, c0.z, v);
        v = fmaf(w3, c0.w, v); v = fmaf(w4, c1.x, v); v = fmaf(w5, c1.y, v);
        if (((cC >> 6) & 3) == wid)
            tile[((cC & 255) << 6) | lane] += fmaxf(v, 0.f);

        v = bb;
        v = fmaf(w0, d0.x, v); v = fmaf(w1, d0.y, v); v = fmaf(w2, d0.z, v);
        v = fmaf(w3, d0.w, v); v = fmaf(w4, d1.x, v); v = fmaf(w5, d1.y, v);
        if (((cD >> 6) & 3) == wid)
            tile[((cD & 255) << 6) | lane] += fmaxf(v, 0.f);
    }
    for (; r < r1; ++r) {
        const float4* q = (const float4*)(rec + (size_t)r * 8);
        const float4 A0 = q[0], A1 = q[1];
        const int c = __float_as_int(A1.z);
        float v = bb;
        v = fmaf(w0, A0.x, v); v = fmaf(w1, A0.y, v); v = fmaf(w2, A0.z, v);
        v = fmaf(w3, A0.w, v); v = fmaf(w4, A1.x, v); v = fmaf(w5, A1.y, v);
        if (((c >> 6) & 3) == wid)
            tile[((c & 255) << 6) | lane] += fmaxf(v, 0.f);
    }
    __syncthreads();

    float4* o4 = (float4*)(out + (size_t)bucket * (256 * OUT_F));
#pragma unroll
    for (int i = 0; i < 16; ++i)
        o4[tid + 256 * i] = t4[tid + 256 * i];
}

// ---- fallback (linked-list path, small ws) ----
__global__ void __launch_bounds__(256)
pfn_build_kernel(const int* __restrict__ idx, int n,
                 int* __restrict__ head, int* __restrict__ nxt) {
    const int p = blockIdx.x * blockDim.x + threadIdx.x;
    if (p >= n) return;
    const int2 ij = ((const int2*)idx)[p];
    const int cell = ij.x * N_PY + ij.y;
    nxt[p] = atomicExch(&head[cell], p);
}

__global__ void pfn_finalize_kernel(const float* __restrict__ acc,
                                    const float* __restrict__ W,
                                    const float* __restrict__ b,
                                    const float* __restrict__ gamma,
                                    const float* __restrict__ beta,
                                    int n,
                                    float* __restrict__ Wp,
                                    float* __restrict__ bp) {
    int f = threadIdx.x;
    double inv_n = 1.0 / (double)n;
    double mx[6];
#pragma unroll
    for (int j = 0; j < 6; ++j) mx[j] = (double)acc[j] * inv_n;
    double C[6][6];
    {
        int k = 0;
        for (int i = 0; i < 6; ++i)
            for (int j = i; j < 6; ++j) {
                double e = (double)acc[6 + k] * inv_n - mx[i] * mx[j];
                C[i][j] = e; C[j][i] = e; ++k;
            }
    }
    double w[6];
#pragma unroll
    for (int j = 0; j < 6; ++j) w[j] = (double)W[f * 6 + j];
    double mean_h = (double)b[f];
#pragma unroll
    for (int j = 0; j < 6; ++j) mean_h += w[j] * mx[j];
    double var_h = 0.0;
    for (int i = 0; i < 6; ++i) {
        double t = 0.0;
        for (int j = 0; j < 6; ++j) t += C[i][j] * w[j];
        var_h += w[i] * t;
    }
    double s = (double)gamma[f] / sqrt(var_h + BN_EPS);
#pragma unroll
    for (int j = 0; j < 6; ++j) Wp[f * 6 + j] = (float)(w[j] * s);
    bp[f] = (float)(((double)b[f] - mean_h) * s + (double)beta[f]);
}

__global__ void __launch_bounds__(256)
pfn_output_kernel(const float* __restrict__ x,
                  const int* __restrict__ head,
                  const int* __restrict__ nxt,
                  const float* __restrict__ Wp,
                  const float* __restrict__ bp,
                  float* __restrict__ out) {
    const int lane = threadIdx.x & 63;
    const int cell = __builtin_amdgcn_readfirstlane(
        (int)((blockIdx.x * blockDim.x + threadIdx.x) >> 6));

    const float w0 = Wp[lane * 6 + 0];
    const float w1 = Wp[lane * 6 + 1];
    const float w2 = Wp[lane * 6 + 2];
    const float w3 = Wp[lane * 6 + 3];
    const float w4 = Wp[lane * 6 + 4];
    const float w5 = Wp[lane * 6 + 5];
    const float bb = bp[lane];

    float s = 0.f;
    int p = head[cell];
    while (p >= 0) {
        const float* xp = x + (size_t)p * 6;
        const int pn = nxt[p];
        float v = bb;
        v = fmaf(w0, xp[0], v);
        v = fmaf(w1, xp[1], v);
        v = fmaf(w2, xp[2], v);
        v = fmaf(w3, xp[3], v);
        v = fmaf(w4, xp[4], v);
        v = fmaf(w5, xp[5], v);
        s += fmaxf(v, 0.0f);
        p = pn;
    }
    out[(size_t)cell * OUT_F + lane] = s;
}

extern "C" void kernel_launch(void* const* d_in, const int* in_sizes, int n_in,
                              void* d_out, int out_size, void* d_ws, size_t ws_size,
                              hipStream_t stream) {
    const float* x     = (const float*)d_in[0];
    const int*   idx   = (const int*)d_in[1];
    const float* W     = (const float*)d_in[2];
    const float* b     = (const float*)d_in[3];
    const float* gamma = (const float*)d_in[4];
    const float* beta  = (const float*)d_in[5];
    float* out = (float*)d_out;

    const int n = in_sizes[0] / IN_F;

    float* acc = (float*)d_ws;
    float* Wp  = (float*)((char*)d_ws + 512);
    float* bp  = Wp + OUT_F * IN_F;

    int*   hist   = (int*)((char*)d_ws + 4096);    // 1024 ints
    int*   S      = (int*)((char*)d_ws + 8192);    // 1025 ints
    int*   cursor = (int*)((char*)d_ws + 12800);   // 1024 ints
    float* rec    = (float*)((char*)d_ws + 16896); // n * 8 floats, 32B recs

    const size_t need = 16896 + (size_t)n * 32;

    if (ws_size >= need) {
        // zero acc + hist (S/cursor fully written by scan kernel)
        hipMemsetAsync(d_ws, 0, 8192, stream);
        pfn_stats_hist_kernel<<<512, 256, 0, stream>>>(x, idx, n, acc, hist);
        pfn_scan_finalize_kernel<<<1, 256, 0, stream>>>(
            hist, S, cursor, n, acc, W, b, gamma, beta, Wp, bp);
        pfn_bin_staged_kernel<<<(n + CHUNK - 1) / CHUNK, 256, 0, stream>>>(
            x, idx, cursor, rec, n);
        pfn_tile_kernel<<<NB, 256, 0, stream>>>(rec, S, Wp, bp, out);
    } else {
        // linked-list fallback
        int* head = (int*)((char*)d_ws + 4096);
        int* nxt  = head + N_CELLS;
        hipMemsetAsync(d_ws, 0, 512, stream);
        pfn_stats_hist_kernel<<<512, 256, 0, stream>>>(x, idx, n, acc, head);
        hipMemsetAsync(head, 0xFF, (size_t)N_CELLS * sizeof(int), stream);
        pfn_finalize_kernel<<<1, 64, 0, stream>>>(acc, W, b, gamma, beta, n, Wp, bp);
        pfn_build_kernel<<<(n + 255) / 256, 256, 0, stream>>>(idx, n, head, nxt);
        pfn_output_kernel<<<N_CELLS / 4, 256, 0, stream>>>(x, head, nxt, Wp, bp, out);
    }
}

// Round 9
// 154.094 us; speedup vs baseline: 3.8154x; 3.5852x over previous
//
#include <hip/hip_runtime.h>

#define N_PY 512
#define IN_F 6
#define OUT_F 64
#define N_CELLS (512 * 512)
#define NBUCKET 4096              // bucket = cell >> 6   (64 cells per bucket)
#define N_SB (NBUCKET * 4)        // sub-bucket = (cell>>6)*4 | (cell&3) = 16384
#define BN_EPS 1e-5

// ---------------------------------------------------------------------------
// ws layout (binned path):
//   [0, 108)         : 27 floats — moment accumulators
//   [512, 2304)      : float Wp[64*6], float bp[64] — BN-folded params
//   [4096, 69632)    : int hist[16384]  — per-sub-bucket point count (pristine)
//   [69632, 135168)  : int S[16384]     — exclusive scan; bin mutates to "end"
//   [135424, +32*n)  : float rec[n*8]   — 32B records {x0..x5, cell, pad}
// fallback (linked-list) reuses [4096...) as head[N_CELLS] + nxt[n].
// ---------------------------------------------------------------------------

__device__ __forceinline__ int sub_bucket(int cell) {
    return ((cell >> 6) << 2) | (cell & 3);
}

__global__ void __launch_bounds__(256)
pfn_stats_hist_kernel(const float* __restrict__ x, const int* __restrict__ idx,
                      int n, float* __restrict__ acc, int* __restrict__ hist) {
    const int tid = blockIdx.x * blockDim.x + threadIdx.x;
    const int stride = gridDim.x * blockDim.x;
    const int npairs = n >> 1;

    float s[27];
#pragma unroll
    for (int k = 0; k < 27; ++k) s[k] = 0.f;

    for (int q = tid; q < npairs; q += stride) {
        const float4* base4 = (const float4*)(x + (size_t)q * 12);
        const float4 a = base4[0];
        const float4 b4 = base4[1];
        const float4 c4 = base4[2];
        const float p0[6] = {a.x, a.y, a.z, a.w, b4.x, b4.y};
        const float p1[6] = {b4.z, b4.w, c4.x, c4.y, c4.z, c4.w};
#pragma unroll
        for (int j = 0; j < 6; ++j) s[j] += p0[j] + p1[j];
        int k = 6;
#pragma unroll
        for (int i = 0; i < 6; ++i)
#pragma unroll
            for (int j = i; j < 6; ++j) {
                s[k] += p0[i] * p0[j] + p1[i] * p1[j];
                ++k;
            }
    }
    if ((n & 1) && tid == 0) {
        const float* p = x + (size_t)(n - 1) * 6;
        float v[6];
#pragma unroll
        for (int j = 0; j < 6; ++j) v[j] = p[j];
#pragma unroll
        for (int j = 0; j < 6; ++j) s[j] += v[j];
        int k = 6;
#pragma unroll
        for (int i = 0; i < 6; ++i)
#pragma unroll
            for (int j = i; j < 6; ++j) { s[k] += v[i] * v[j]; ++k; }
    }

    // sub-bucket histogram: 2 points per int4, fire-and-forget atomics (64KB)
    for (int q = tid; q < npairs; q += stride) {
        const int4 ij2 = ((const int4*)idx)[q];
        atomicAdd(&hist[sub_bucket(ij2.x * N_PY + ij2.y)], 1);
        atomicAdd(&hist[sub_bucket(ij2.z * N_PY + ij2.w)], 1);
    }
    if ((n & 1) && tid == 0) {
        const int2 ij = ((const int2*)idx)[n - 1];
        atomicAdd(&hist[sub_bucket(ij.x * N_PY + ij.y)], 1);
    }

#pragma unroll
    for (int off = 32; off > 0; off >>= 1)
#pragma unroll
        for (int k = 0; k < 27; ++k) s[k] += __shfl_down(s[k], off, 64);

    __shared__ float lds[4][27];
    const int wid = threadIdx.x >> 6;
    const int lane = threadIdx.x & 63;
    if (lane == 0)
#pragma unroll
        for (int k = 0; k < 27; ++k) lds[wid][k] = s[k];
    __syncthreads();

    if (threadIdx.x < 27) {
        const int k = threadIdx.x;
        const float v = lds[0][k] + lds[1][k] + lds[2][k] + lds[3][k];
        atomicAdd(&acc[k], v);
    }
}

// single block, 1024 threads: exclusive scan of hist[16384] -> S (start
// offsets; bin will mutate S to "end"), plus BN-param fold on threads 0..63.
__global__ void __launch_bounds__(1024)
pfn_scan_finalize_kernel(const int* __restrict__ hist, int* __restrict__ S,
                         int n,
                         const float* __restrict__ acc,
                         const float* __restrict__ W,
                         const float* __restrict__ b,
                         const float* __restrict__ gamma,
                         const float* __restrict__ beta,
                         float* __restrict__ Wp, float* __restrict__ bp) {
    const int tid = threadIdx.x;   // 1024 threads x 16 entries = 16384
    int v[16];
    const int4* h4 = (const int4*)(hist + tid * 16);
#pragma unroll
    for (int g = 0; g < 4; ++g) {
        const int4 q = h4[g];
        v[g * 4 + 0] = q.x; v[g * 4 + 1] = q.y;
        v[g * 4 + 2] = q.z; v[g * 4 + 3] = q.w;
    }
    int pre[16];
    int tot = 0;
#pragma unroll
    for (int k = 0; k < 16; ++k) { pre[k] = tot; tot += v[k]; }

    __shared__ int sc[1024];
    sc[tid] = tot;
    __syncthreads();
#pragma unroll
    for (int off = 1; off < 1024; off <<= 1) {
        const int add = (tid >= off) ? sc[tid - off] : 0;
        __syncthreads();
        sc[tid] += add;
        __syncthreads();
    }
    const int excl = sc[tid] - tot;
#pragma unroll
    for (int k = 0; k < 16; ++k)
        S[tid * 16 + k] = excl + pre[k];

    // ---- BN-fold ----
    if (tid < 64) {
        const int f = tid;
        double inv_n = 1.0 / (double)n;
        double mx[6];
#pragma unroll
        for (int j = 0; j < 6; ++j) mx[j] = (double)acc[j] * inv_n;
        double C[6][6];
        {
            int k = 0;
            for (int i = 0; i < 6; ++i)
                for (int j = i; j < 6; ++j) {
                    double e = (double)acc[6 + k] * inv_n - mx[i] * mx[j];
                    C[i][j] = e; C[j][i] = e; ++k;
                }
        }
        double w[6];
#pragma unroll
        for (int j = 0; j < 6; ++j) w[j] = (double)W[f * 6 + j];
        double mean_h = (double)b[f];
#pragma unroll
        for (int j = 0; j < 6; ++j) mean_h += w[j] * mx[j];
        double var_h = 0.0;
        for (int i = 0; i < 6; ++i) {
            double t = 0.0;
            for (int j = 0; j < 6; ++j) t += C[i][j] * w[j];
            var_h += w[i] * t;
        }
        double sgn = (double)gamma[f] / sqrt(var_h + BN_EPS);
#pragma unroll
        for (int j = 0; j < 6; ++j) Wp[f * 6 + j] = (float)(w[j] * sgn);
        bp[f] = (float)(((double)b[f] - mean_h) * sgn + (double)beta[f]);
    }
}

// bin: 4 points/thread. All 4 LLC atomics issued back-to-back (independent,
// overlap their ~700cy latency), THEN the 8 scattered stores. Mutates S.
__global__ void __launch_bounds__(256)
pfn_bin_kernel(const float* __restrict__ x, const int* __restrict__ idx,
               int* __restrict__ S, float* __restrict__ rec, int n) {
    const int t = blockIdx.x * blockDim.x + threadIdx.x;
    const int p0 = t * 4;
    if (p0 >= n) return;

    if (p0 + 4 <= n) {
        const int4 ij01 = ((const int4*)idx)[t * 2];
        const int4 ij23 = ((const int4*)idx)[t * 2 + 1];
        const int c0 = ij01.x * N_PY + ij01.y;
        const int c1 = ij01.z * N_PY + ij01.w;
        const int c2 = ij23.x * N_PY + ij23.y;
        const int c3 = ij23.z * N_PY + ij23.w;

        const float4* xx = (const float4*)(x + (size_t)p0 * 6);
        const float4 x0 = xx[0], x1 = xx[1], x2 = xx[2];
        const float4 x3 = xx[3], x4 = xx[4], x5 = xx[5];

        // 4 independent atomics in flight
        const int pos0 = atomicAdd(&S[sub_bucket(c0)], 1);
        const int pos1 = atomicAdd(&S[sub_bucket(c1)], 1);
        const int pos2 = atomicAdd(&S[sub_bucket(c2)], 1);
        const int pos3 = atomicAdd(&S[sub_bucket(c3)], 1);

        float4* d0 = (float4*)(rec + (size_t)pos0 * 8);
        d0[0] = float4{x0.x, x0.y, x0.z, x0.w};
        d0[1] = float4{x1.x, x1.y, __int_as_float(c0), 0.f};
        float4* d1 = (float4*)(rec + (size_t)pos1 * 8);
        d1[0] = float4{x1.z, x1.w, x2.x, x2.y};
        d1[1] = float4{x2.z, x2.w, __int_as_float(c1), 0.f};
        float4* d2 = (float4*)(rec + (size_t)pos2 * 8);
        d2[0] = float4{x3.x, x3.y, x3.z, x3.w};
        d2[1] = float4{x4.x, x4.y, __int_as_float(c2), 0.f};
        float4* d3 = (float4*)(rec + (size_t)pos3 * 8);
        d3[0] = float4{x4.z, x4.w, x5.x, x5.y};
        d3[1] = float4{x5.z, x5.w, __int_as_float(c3), 0.f};
    } else {
        for (int k = 0; k < 4; ++k) {
            const int p = p0 + k;
            if (p >= n) break;
            const int2 ij = ((const int2*)idx)[p];
            const int cell = ij.x * N_PY + ij.y;
            const int pos = atomicAdd(&S[sub_bucket(cell)], 1);
            const float2* xp = (const float2*)(x + (size_t)p * 6);
            const float2 a = xp[0], b2 = xp[1], c = xp[2];
            float4* d = (float4*)(rec + (size_t)pos * 8);
            d[0] = float4{a.x, a.y, b2.x, b2.y};
            d[1] = float4{c.x, c.y, __int_as_float(cell), 0.f};
        }
    }
}

// one block per 64-cell bucket, 4 waves. Wave w owns sub-bucket (bucket*4+w),
// whose cells satisfy (cell&3)==w -> plain LDS += with no races.
// Records are consumed via cooperative staging: each wave's contiguous ~2KB
// segment chunk is loaded with 2 coalesced wave-wide float4 loads into an LDS
// stage, then read back as uniform ds_read_b128 broadcasts (no uniform-global-
// load latency chains -- the R8 defect). Coalesced 16KB flush; out written
// exactly once -> no d_out memset.
__global__ void __launch_bounds__(256)
pfn_tile_kernel(const float* __restrict__ rec, const int* __restrict__ Send,
                const int* __restrict__ hist,
                const float* __restrict__ Wp, const float* __restrict__ bp,
                float* __restrict__ out) {
    __shared__ float tile[64 * OUT_F];    // 16 KB
    __shared__ float stage[4][512];       // 8 KB: 4 waves x 64 records x 8 f
    const int tid = threadIdx.x;
    const int lane = tid & 63;
    const int wid = tid >> 6;
    const int bucket = blockIdx.x;

    float4* t4 = (float4*)tile;
#pragma unroll
    for (int i = 0; i < 4; ++i)
        t4[tid + 256 * i] = float4{0.f, 0.f, 0.f, 0.f};

    const float w0 = Wp[lane * 6 + 0];
    const float w1 = Wp[lane * 6 + 1];
    const float w2 = Wp[lane * 6 + 2];
    const float w3 = Wp[lane * 6 + 3];
    const float w4 = Wp[lane * 6 + 4];
    const float w5 = Wp[lane * 6 + 5];
    const float bb = bp[lane];

    __syncthreads();

    const int sb = (bucket << 2) | wid;
    const int cnt = hist[sb];
    const int r0 = Send[sb] - cnt;        // S was mutated to "end" by bin
    float4* stg = (float4*)stage[wid];

    for (int chunk = 0; chunk < cnt; chunk += 64) {
        const int m = min(64, cnt - chunk);
        const int nf4 = m * 2;
        const float4* src = (const float4*)(rec + (size_t)(r0 + chunk) * 8);
        // cooperative coalesced load of the chunk (wave-private stage)
        if (lane < nf4) stg[lane] = src[lane];
        if (lane + 64 < nf4) stg[lane + 64] = src[lane + 64];
        // intra-wave LDS write->read ordering via compiler-inserted waitcnt
#pragma unroll 4
        for (int j = 0; j < m; ++j) {
            const float4 A0 = stg[2 * j];       // uniform ds_read: broadcast
            const float4 A1 = stg[2 * j + 1];
            const int c = __float_as_int(A1.z);
            float v = bb;
            v = fmaf(w0, A0.x, v); v = fmaf(w1, A0.y, v); v = fmaf(w2, A0.z, v);
            v = fmaf(w3, A0.w, v); v = fmaf(w4, A1.x, v); v = fmaf(w5, A1.y, v);
            tile[((c & 63) << 6) | lane] += fmaxf(v, 0.f);
        }
    }
    __syncthreads();

    float4* o4 = (float4*)(out + (size_t)bucket * (64 * OUT_F));
#pragma unroll
    for (int i = 0; i < 4; ++i)
        o4[tid + 256 * i] = t4[tid + 256 * i];
}

// ---- fallback (linked-list path, small ws) ----
__global__ void __launch_bounds__(256)
pfn_build_kernel(const int* __restrict__ idx, int n,
                 int* __restrict__ head, int* __restrict__ nxt) {
    const int p = blockIdx.x * blockDim.x + threadIdx.x;
    if (p >= n) return;
    const int2 ij = ((const int2*)idx)[p];
    const int cell = ij.x * N_PY + ij.y;
    nxt[p] = atomicExch(&head[cell], p);
}

__global__ void pfn_finalize_kernel(const float* __restrict__ acc,
                                    const float* __restrict__ W,
                                    const float* __restrict__ b,
                                    const float* __restrict__ gamma,
                                    const float* __restrict__ beta,
                                    int n,
                                    float* __restrict__ Wp,
                                    float* __restrict__ bp) {
    int f = threadIdx.x;
    double inv_n = 1.0 / (double)n;
    double mx[6];
#pragma unroll
    for (int j = 0; j < 6; ++j) mx[j] = (double)acc[j] * inv_n;
    double C[6][6];
    {
        int k = 0;
        for (int i = 0; i < 6; ++i)
            for (int j = i; j < 6; ++j) {
                double e = (double)acc[6 + k] * inv_n - mx[i] * mx[j];
                C[i][j] = e; C[j][i] = e; ++k;
            }
    }
    double w[6];
#pragma unroll
    for (int j = 0; j < 6; ++j) w[j] = (double)W[f * 6 + j];
    double mean_h = (double)b[f];
#pragma unroll
    for (int j = 0; j < 6; ++j) mean_h += w[j] * mx[j];
    double var_h = 0.0;
    for (int i = 0; i < 6; ++i) {
        double t = 0.0;
        for (int j = 0; j < 6; ++j) t += C[i][j] * w[j];
        var_h += w[i] * t;
    }
    double s = (double)gamma[f] / sqrt(var_h + BN_EPS);
#pragma unroll
    for (int j = 0; j < 6; ++j) Wp[f * 6 + j] = (float)(w[j] * s);
    bp[f] = (float)(((double)b[f] - mean_h) * s + (double)beta[f]);
}

__global__ void __launch_bounds__(256)
pfn_output_kernel(const float* __restrict__ x,
                  const int* __restrict__ head,
                  const int* __restrict__ nxt,
                  const float* __restrict__ Wp,
                  const float* __restrict__ bp,
                  float* __restrict__ out) {
    const int lane = threadIdx.x & 63;
    const int cell = __builtin_amdgcn_readfirstlane(
        (int)((blockIdx.x * blockDim.x + threadIdx.x) >> 6));

    const float w0 = Wp[lane * 6 + 0];
    const float w1 = Wp[lane * 6 + 1];
    const float w2 = Wp[lane * 6 + 2];
    const float w3 = Wp[lane * 6 + 3];
    const float w4 = Wp[lane * 6 + 4];
    const float w5 = Wp[lane * 6 + 5];
    const float bb = bp[lane];

    float s = 0.f;
    int p = head[cell];
    while (p >= 0) {
        const float* xp = x + (size_t)p * 6;
        const int pn = nxt[p];
        float v = bb;
        v = fmaf(w0, xp[0], v);
        v = fmaf(w1, xp[1], v);
        v = fmaf(w2, xp[2], v);
        v = fmaf(w3, xp[3], v);
        v = fmaf(w4, xp[4], v);
        v = fmaf(w5, xp[5], v);
        s += fmaxf(v, 0.0f);
        p = pn;
    }
    out[(size_t)cell * OUT_F + lane] = s;
}

extern "C" void kernel_launch(void* const* d_in, const int* in_sizes, int n_in,
                              void* d_out, int out_size, void* d_ws, size_t ws_size,
                              hipStream_t stream) {
    const float* x     = (const float*)d_in[0];
    const int*   idx   = (const int*)d_in[1];
    const float* W     = (const float*)d_in[2];
    const float* b     = (const float*)d_in[3];
    const float* gamma = (const float*)d_in[4];
    const float* beta  = (const float*)d_in[5];
    float* out = (float*)d_out;

    const int n = in_sizes[0] / IN_F;

    float* acc = (float*)d_ws;
    float* Wp  = (float*)((char*)d_ws + 512);
    float* bp  = Wp + OUT_F * IN_F;

    int*   hist = (int*)((char*)d_ws + 4096);     // 16384 ints (64KB)
    int*   S    = (int*)((char*)d_ws + 69632);    // 16384 ints (64KB)
    float* rec  = (float*)((char*)d_ws + 135424); // n*8 floats, 32B records

    const size_t need = 135424 + (size_t)n * 32;

    if (ws_size >= need) {
        // zero acc + hist (one 68KB memset; Wp/bp/S rewritten by scan kernel)
        hipMemsetAsync(d_ws, 0, 69632, stream);
        pfn_stats_hist_kernel<<<512, 256, 0, stream>>>(x, idx, n, acc, hist);
        pfn_scan_finalize_kernel<<<1, 1024, 0, stream>>>(
            hist, S, n, acc, W, b, gamma, beta, Wp, bp);
        pfn_bin_kernel<<<(n + 1023) / 1024, 256, 0, stream>>>(x, idx, S, rec, n);
        pfn_tile_kernel<<<NBUCKET, 256, 0, stream>>>(rec, S, hist, Wp, bp, out);
    } else {
        // linked-list fallback
        int* head = (int*)((char*)d_ws + 4096);
        int* nxt  = head + N_CELLS;
        hipMemsetAsync(d_ws, 0, 512, stream);
        pfn_stats_hist_kernel<<<512, 256, 0, stream>>>(x, idx, n, acc, head);
        hipMemsetAsync(head, 0xFF, (size_t)N_CELLS * sizeof(int), stream);
        pfn_finalize_kernel<<<1, 64, 0, stream>>>(acc, W, b, gamma, beta, n, Wp, bp);
        pfn_build_kernel<<<(n + 255) / 256, 256, 0, stream>>>(idx, n, head, nxt);
        pfn_output_kernel<<<N_CELLS / 4, 256, 0, stream>>>(x, head, nxt, Wp, bp, out);
    }
}

// Round 11
// 147.971 us; speedup vs baseline: 3.9733x; 1.0414x over previous
//
#include <hip/hip_runtime.h>
#include <hip/hip_fp16.h>

#define N_PY 512
#define IN_F 6
#define OUT_F 64
#define N_CELLS (512 * 512)
#define NBUCKET 4096              // bucket = cell >> 6   (64 cells per bucket)
#define N_SB (NBUCKET * 4)        // sub-bucket = (cell>>6)*4 | (cell&3) = 16384
#define NF (N_SB * 8)             // flattened (sub-bucket, slice) = 131072
#define BN_EPS 1e-5

// ---------------------------------------------------------------------------
// ws layout (binned path):
//   [0, 108)            : 27 floats — moment accumulators
//   [512, 2304)         : float Wp[64*6], float bp[64] — BN-folded params
//   [4096, 528384)      : int H[131072]     — count per (sub-bucket*8 + slice)
//   [528384, 1052672)   : int base[131072]  — scanA: block-local excl scan
//   [1052672, 1576960)  : int cursor[131072]— mutable copy of base for binning
//   [1576960, 1577472)  : int bsums[128]    — scanB: excl-scanned block sums
//   [1577984, +16*n)    : uint4 rec[n]      — 16B records {6 x f16, local}
// SLICE CONTRACT: point p is binned by bin-block p/1024 into slice (p/1024)&7.
// The histogram MUST use the same per-point mapping (R10 bug: it used the
// stats kernel's own blockIdx, a different mapping -> cursor overflow).
// fallback (linked-list) reuses [4096...) as head[N_CELLS] + nxt[n].
// ---------------------------------------------------------------------------

__device__ __forceinline__ int sub_bucket(int cell) {
    return ((cell >> 6) << 2) | (cell & 3);
}

__device__ __forceinline__ unsigned pack2h(float a, float b) {
    __half ha = __float2half_rn(a), hb = __float2half_rn(b);
    unsigned short ua = *reinterpret_cast<unsigned short*>(&ha);
    unsigned short ub = *reinterpret_cast<unsigned short*>(&hb);
    return (unsigned)ua | ((unsigned)ub << 16);
}

__device__ __forceinline__ float2 unpack2h(unsigned u) {
    __half2 h = *reinterpret_cast<__half2*>(&u);
    return __half22float2(h);
}

__global__ void __launch_bounds__(256)
pfn_stats_hist_kernel(const float* __restrict__ x, const int* __restrict__ idx,
                      int n, float* __restrict__ acc, int* __restrict__ H) {
    const int tid = blockIdx.x * blockDim.x + threadIdx.x;
    const int stride = gridDim.x * blockDim.x;
    const int npairs = n >> 1;

    float s[27];
#pragma unroll
    for (int k = 0; k < 27; ++k) s[k] = 0.f;

    for (int q = tid; q < npairs; q += stride) {
        const float4* base4 = (const float4*)(x + (size_t)q * 12);
        const float4 a = base4[0];
        const float4 b4 = base4[1];
        const float4 c4 = base4[2];
        const float p0[6] = {a.x, a.y, a.z, a.w, b4.x, b4.y};
        const float p1[6] = {b4.z, b4.w, c4.x, c4.y, c4.z, c4.w};
#pragma unroll
        for (int j = 0; j < 6; ++j) s[j] += p0[j] + p1[j];
        int k = 6;
#pragma unroll
        for (int i = 0; i < 6; ++i)
#pragma unroll
            for (int j = i; j < 6; ++j) {
                s[k] += p0[i] * p0[j] + p1[i] * p1[j];
                ++k;
            }
    }
    if ((n & 1) && tid == 0) {
        const float* p = x + (size_t)(n - 1) * 6;
        float v[6];
#pragma unroll
        for (int j = 0; j < 6; ++j) v[j] = p[j];
#pragma unroll
        for (int j = 0; j < 6; ++j) s[j] += v[j];
        int k = 6;
#pragma unroll
        for (int i = 0; i < 6; ++i)
#pragma unroll
            for (int j = i; j < 6; ++j) { s[k] += v[i] * v[j]; ++k; }
    }

    // per-(sub-bucket, slice) histogram. slice derived from POINT INDEX to
    // match the bin kernel: points 2q,2q+1 -> slice ((2q)>>10)&7 = (q>>9)&7.
    for (int q = tid; q < npairs; q += stride) {
        const int4 ij2 = ((const int4*)idx)[q];
        const int sl = (q >> 9) & 7;
        atomicAdd(&H[sub_bucket(ij2.x * N_PY + ij2.y) * 8 + sl], 1);
        atomicAdd(&H[sub_bucket(ij2.z * N_PY + ij2.w) * 8 + sl], 1);
    }
    if ((n & 1) && tid == 0) {
        const int2 ij = ((const int2*)idx)[n - 1];
        const int sl = ((n - 1) >> 10) & 7;
        atomicAdd(&H[sub_bucket(ij.x * N_PY + ij.y) * 8 + sl], 1);
    }

#pragma unroll
    for (int off = 32; off > 0; off >>= 1)
#pragma unroll
        for (int k = 0; k < 27; ++k) s[k] += __shfl_down(s[k], off, 64);

    __shared__ float lds[4][27];
    const int wid = threadIdx.x >> 6;
    const int lane = threadIdx.x & 63;
    if (lane == 0)
#pragma unroll
        for (int k = 0; k < 27; ++k) lds[wid][k] = s[k];
    __syncthreads();

    if (threadIdx.x < 27) {
        const int k = threadIdx.x;
        const float v = lds[0][k] + lds[1][k] + lds[2][k] + lds[3][k];
        atomicAdd(&acc[k], v);
    }
}

// scanA: 128 blocks x 1024 entries of H. Writes block-local exclusive scan to
// base[] AND cursor[], per-block total to bsums[].
__global__ void __launch_bounds__(256)
pfn_scanA_kernel(const int* __restrict__ H, int* __restrict__ base,
                 int* __restrict__ cursor, int* __restrict__ bsums) {
    const int tid = threadIdx.x;
    const int b = blockIdx.x;
    const int4 v = ((const int4*)(H + b * 1024))[tid];
    const int t = v.x + v.y + v.z + v.w;

    __shared__ int sc[256];
    sc[tid] = t;
    __syncthreads();
#pragma unroll
    for (int off = 1; off < 256; off <<= 1) {
        const int add = (tid >= off) ? sc[tid - off] : 0;
        __syncthreads();
        sc[tid] += add;
        __syncthreads();
    }
    const int incl = sc[tid];
    const int excl = incl - t;

    int4 o;
    o.x = excl;
    o.y = o.x + v.x;
    o.z = o.y + v.y;
    o.w = o.z + v.z;
    ((int4*)(base + b * 1024))[tid] = o;
    ((int4*)(cursor + b * 1024))[tid] = o;
    if (tid == 255) bsums[b] = incl;
}

// scanB: 1 block: exclusive scan of the 128 block sums in place + BN fold.
__global__ void __launch_bounds__(128)
pfn_scanB_kernel(int* __restrict__ bsums, int n,
                 const float* __restrict__ acc,
                 const float* __restrict__ W,
                 const float* __restrict__ b,
                 const float* __restrict__ gamma,
                 const float* __restrict__ beta,
                 float* __restrict__ Wp, float* __restrict__ bp) {
    const int tid = threadIdx.x;
    const int t = bsums[tid];
    __shared__ int sc[128];
    sc[tid] = t;
    __syncthreads();
#pragma unroll
    for (int off = 1; off < 128; off <<= 1) {
        const int add = (tid >= off) ? sc[tid - off] : 0;
        __syncthreads();
        sc[tid] += add;
        __syncthreads();
    }
    bsums[tid] = sc[tid] - t;   // exclusive

    if (tid < 64) {
        const int f = tid;
        double inv_n = 1.0 / (double)n;
        double mx[6];
#pragma unroll
        for (int j = 0; j < 6; ++j) mx[j] = (double)acc[j] * inv_n;
        double C[6][6];
        {
            int k = 0;
            for (int i = 0; i < 6; ++i)
                for (int j = i; j < 6; ++j) {
                    double e = (double)acc[6 + k] * inv_n - mx[i] * mx[j];
                    C[i][j] = e; C[j][i] = e; ++k;
                }
        }
        double w[6];
#pragma unroll
        for (int j = 0; j < 6; ++j) w[j] = (double)W[f * 6 + j];
        double mean_h = (double)b[f];
#pragma unroll
        for (int j = 0; j < 6; ++j) mean_h += w[j] * mx[j];
        double var_h = 0.0;
        for (int i = 0; i < 6; ++i) {
            double tt = 0.0;
            for (int j = 0; j < 6; ++j) tt += C[i][j] * w[j];
            var_h += w[i] * tt;
        }
        double sgn = (double)gamma[f] / sqrt(var_h + BN_EPS);
#pragma unroll
        for (int j = 0; j < 6; ++j) Wp[f * 6 + j] = (float)(w[j] * sgn);
        bp[f] = (float)(((double)b[f] - mean_h) * sgn + (double)beta[f]);
    }
}

// bin: 4 points/thread, slice = blockIdx&7 == (p/1024)&7 (block covers 1024
// consecutive points). XCD-local rec region -> L2 write combining.
// 4 independent atomics in flight; 16B f16 records.
__global__ void __launch_bounds__(256)
pfn_bin_kernel(const float* __restrict__ x, const int* __restrict__ idx,
               int* __restrict__ cursor, const int* __restrict__ bsums,
               uint4* __restrict__ rec, int n) {
    const int t = blockIdx.x * blockDim.x + threadIdx.x;
    const int p0 = t * 4;
    if (p0 >= n) return;
    const int slice = blockIdx.x & 7;

    if (p0 + 4 <= n) {
        const int4 ij01 = ((const int4*)idx)[t * 2];
        const int4 ij23 = ((const int4*)idx)[t * 2 + 1];
        const int c0 = ij01.x * N_PY + ij01.y;
        const int c1 = ij01.z * N_PY + ij01.w;
        const int c2 = ij23.x * N_PY + ij23.y;
        const int c3 = ij23.z * N_PY + ij23.w;
        const int f0 = sub_bucket(c0) * 8 + slice;
        const int f1 = sub_bucket(c1) * 8 + slice;
        const int f2 = sub_bucket(c2) * 8 + slice;
        const int f3 = sub_bucket(c3) * 8 + slice;

        const float4* xx = (const float4*)(x + (size_t)p0 * 6);
        const float4 x0 = xx[0], x1 = xx[1], x2 = xx[2];
        const float4 x3 = xx[3], x4 = xx[4], x5 = xx[5];

        // 4 independent atomics in flight
        const int pos0 = atomicAdd(&cursor[f0], 1) + bsums[f0 >> 10];
        const int pos1 = atomicAdd(&cursor[f1], 1) + bsums[f1 >> 10];
        const int pos2 = atomicAdd(&cursor[f2], 1) + bsums[f2 >> 10];
        const int pos3 = atomicAdd(&cursor[f3], 1) + bsums[f3 >> 10];

        rec[pos0] = uint4{pack2h(x0.x, x0.y), pack2h(x0.z, x0.w),
                          pack2h(x1.x, x1.y), (unsigned)((c0 >> 2) & 15)};
        rec[pos1] = uint4{pack2h(x1.z, x1.w), pack2h(x2.x, x2.y),
                          pack2h(x2.z, x2.w), (unsigned)((c1 >> 2) & 15)};
        rec[pos2] = uint4{pack2h(x3.x, x3.y), pack2h(x3.z, x3.w),
                          pack2h(x4.x, x4.y), (unsigned)((c2 >> 2) & 15)};
        rec[pos3] = uint4{pack2h(x4.z, x4.w), pack2h(x5.x, x5.y),
                          pack2h(x5.z, x5.w), (unsigned)((c3 >> 2) & 15)};
    } else {
        for (int k = 0; k < 4; ++k) {
            const int p = p0 + k;
            if (p >= n) break;
            const int2 ij = ((const int2*)idx)[p];
            const int cell = ij.x * N_PY + ij.y;
            const int f = sub_bucket(cell) * 8 + slice;
            const int pos = atomicAdd(&cursor[f], 1) + bsums[f >> 10];
            const float2* xp = (const float2*)(x + (size_t)p * 6);
            const float2 a = xp[0], b2 = xp[1], c = xp[2];
            rec[pos] = uint4{pack2h(a.x, a.y), pack2h(b2.x, b2.y),
                             pack2h(c.x, c.y), (unsigned)((cell >> 2) & 15)};
        }
    }
}

// one block per 64-cell bucket, 4 waves. Wave w owns sub-bucket (bucket*4+w)
// (cells with (cell&3)==w) -> plain LDS += with no races. Each wave's record
// segment (contiguous, slice-minor order) is staged chunk-wise with one
// coalesced uint4 load per lane, then consumed as uniform ds_read broadcasts.
__global__ void __launch_bounds__(256)
pfn_tile_kernel(const uint4* __restrict__ rec,
                const int* __restrict__ base, const int* __restrict__ bsums,
                const float* __restrict__ Wp, const float* __restrict__ bp,
                float* __restrict__ out, int n) {
    __shared__ float tile[64 * OUT_F];    // 16 KB
    __shared__ uint4 stage[4][64];        // 4 KB
    const int tid = threadIdx.x;
    const int lane = tid & 63;
    const int wid = tid >> 6;
    const int bucket = blockIdx.x;

    float4* t4 = (float4*)tile;
#pragma unroll
    for (int i = 0; i < 4; ++i)
        t4[tid + 256 * i] = float4{0.f, 0.f, 0.f, 0.f};

    const float w0 = Wp[lane * 6 + 0];
    const float w1 = Wp[lane * 6 + 1];
    const float w2 = Wp[lane * 6 + 2];
    const float w3 = Wp[lane * 6 + 3];
    const float w4 = Wp[lane * 6 + 4];
    const float w5 = Wp[lane * 6 + 5];
    const float bb = bp[lane];

    __syncthreads();

    const int sb = (bucket << 2) | wid;
    const int f0 = sb * 8;
    const int r0 = base[f0] + bsums[f0 >> 10];
    const int rend = (sb == N_SB - 1) ? n
                     : base[f0 + 8] + bsums[(f0 + 8) >> 10];
    const int cnt = rend - r0;
    uint4* stg = stage[wid];

    for (int chunk = 0; chunk < cnt; chunk += 64) {
        const int m = min(64, cnt - chunk);
        const uint4* src = rec + (size_t)(r0 + chunk);
        if (lane < m) stg[lane] = src[lane];   // coalesced 16B/lane
#pragma unroll 4
        for (int j = 0; j < m; ++j) {
            const uint4 q = stg[j];            // uniform ds_read: broadcast
            const float2 f01 = unpack2h(q.x);
            const float2 f23 = unpack2h(q.y);
            const float2 f45 = unpack2h(q.z);
            float v = bb;
            v = fmaf(w0, f01.x, v); v = fmaf(w1, f01.y, v);
            v = fmaf(w2, f23.x, v); v = fmaf(w3, f23.y, v);
            v = fmaf(w4, f45.x, v); v = fmaf(w5, f45.y, v);
            tile[((((int)q.w << 2) | wid) << 6) | lane] += fmaxf(v, 0.f);
        }
    }
    __syncthreads();

    float4* o4 = (float4*)(out + (size_t)bucket * (64 * OUT_F));
#pragma unroll
    for (int i = 0; i < 4; ++i)
        o4[tid + 256 * i] = t4[tid + 256 * i];
}

// ---- fallback (linked-list path, small ws) ----
__global__ void __launch_bounds__(256)
pfn_build_kernel(const int* __restrict__ idx, int n,
                 int* __restrict__ head, int* __restrict__ nxt) {
    const int p = blockIdx.x * blockDim.x + threadIdx.x;
    if (p >= n) return;
    const int2 ij = ((const int2*)idx)[p];
    const int cell = ij.x * N_PY + ij.y;
    nxt[p] = atomicExch(&head[cell], p);
}

__global__ void pfn_finalize_kernel(const float* __restrict__ acc,
                                    const float* __restrict__ W,
                                    const float* __restrict__ b,
                                    const float* __restrict__ gamma,
                                    const float* __restrict__ beta,
                                    int n,
                                    float* __restrict__ Wp,
                                    float* __restrict__ bp) {
    int f = threadIdx.x;
    double inv_n = 1.0 / (double)n;
    double mx[6];
#pragma unroll
    for (int j = 0; j < 6; ++j) mx[j] = (double)acc[j] * inv_n;
    double C[6][6];
    {
        int k = 0;
        for (int i = 0; i < 6; ++i)
            for (int j = i; j < 6; ++j) {
                double e = (double)acc[6 + k] * inv_n - mx[i] * mx[j];
                C[i][j] = e; C[j][i] = e; ++k;
            }
    }
    double w[6];
#pragma unroll
    for (int j = 0; j < 6; ++j) w[j] = (double)W[f * 6 + j];
    double mean_h = (double)b[f];
#pragma unroll
    for (int j = 0; j < 6; ++j) mean_h += w[j] * mx[j];
    double var_h = 0.0;
    for (int i = 0; i < 6; ++i) {
        double t = 0.0;
        for (int j = 0; j < 6; ++j) t += C[i][j] * w[j];
        var_h += w[i] * t;
    }
    double s = (double)gamma[f] / sqrt(var_h + BN_EPS);
#pragma unroll
    for (int j = 0; j < 6; ++j) Wp[f * 6 + j] = (float)(w[j] * s);
    bp[f] = (float)(((double)b[f] - mean_h) * s + (double)beta[f]);
}

__global__ void __launch_bounds__(256)
pfn_output_kernel(const float* __restrict__ x,
                  const int* __restrict__ head,
                  const int* __restrict__ nxt,
                  const float* __restrict__ Wp,
                  const float* __restrict__ bp,
                  float* __restrict__ out) {
    const int lane = threadIdx.x & 63;
    const int cell = __builtin_amdgcn_readfirstlane(
        (int)((blockIdx.x * blockDim.x + threadIdx.x) >> 6));

    const float w0 = Wp[lane * 6 + 0];
    const float w1 = Wp[lane * 6 + 1];
    const float w2 = Wp[lane * 6 + 2];
    const float w3 = Wp[lane * 6 + 3];
    const float w4 = Wp[lane * 6 + 4];
    const float w5 = Wp[lane * 6 + 5];
    const float bb = bp[lane];

    float s = 0.f;
    int p = head[cell];
    while (p >= 0) {
        const float* xp = x + (size_t)p * 6;
        const int pn = nxt[p];
        float v = bb;
        v = fmaf(w0, xp[0], v);
        v = fmaf(w1, xp[1], v);
        v = fmaf(w2, xp[2], v);
        v = fmaf(w3, xp[3], v);
        v = fmaf(w4, xp[4], v);
        v = fmaf(w5, xp[5], v);
        s += fmaxf(v, 0.0f);
        p = pn;
    }
    out[(size_t)cell * OUT_F + lane] = s;
}

extern "C" void kernel_launch(void* const* d_in, const int* in_sizes, int n_in,
                              void* d_out, int out_size, void* d_ws, size_t ws_size,
                              hipStream_t stream) {
    const float* x     = (const float*)d_in[0];
    const int*   idx   = (const int*)d_in[1];
    const float* W     = (const float*)d_in[2];
    const float* b     = (const float*)d_in[3];
    const float* gamma = (const float*)d_in[4];
    const float* beta  = (const float*)d_in[5];
    float* out = (float*)d_out;

    const int n = in_sizes[0] / IN_F;

    float* acc = (float*)d_ws;
    float* Wp  = (float*)((char*)d_ws + 512);
    float* bp  = Wp + OUT_F * IN_F;

    int*   H      = (int*)((char*)d_ws + 4096);      // 131072 ints (512KB)
    int*   base   = (int*)((char*)d_ws + 528384);    // 131072 ints (512KB)
    int*   cursor = (int*)((char*)d_ws + 1052672);   // 131072 ints (512KB)
    int*   bsums  = (int*)((char*)d_ws + 1576960);   // 128 ints
    uint4* rec    = (uint4*)((char*)d_ws + 1577984); // n x 16B records

    const size_t need = 1577984 + (size_t)n * 16;

    if (ws_size >= need) {
        // zero acc + H (one 528KB memset; others fully rewritten per call)
        hipMemsetAsync(d_ws, 0, 528384, stream);
        pfn_stats_hist_kernel<<<1024, 256, 0, stream>>>(x, idx, n, acc, H);
        pfn_scanA_kernel<<<128, 256, 0, stream>>>(H, base, cursor, bsums);
        pfn_scanB_kernel<<<1, 128, 0, stream>>>(bsums, n, acc, W, b, gamma,
                                                beta, Wp, bp);
        pfn_bin_kernel<<<(n + 1023) / 1024, 256, 0, stream>>>(
            x, idx, cursor, bsums, rec, n);
        pfn_tile_kernel<<<NBUCKET, 256, 0, stream>>>(rec, base, bsums, Wp, bp,
                                                     out, n);
    } else {
        // linked-list fallback
        int* head = (int*)((char*)d_ws + 4096);
        int* nxt  = head + N_CELLS;
        hipMemsetAsync(d_ws, 0, 512, stream);
        pfn_stats_hist_kernel<<<1024, 256, 0, stream>>>(x, idx, n, acc, head);
        hipMemsetAsync(head, 0xFF, (size_t)N_CELLS * sizeof(int), stream);
        pfn_finalize_kernel<<<1, 64, 0, stream>>>(acc, W, b, gamma, beta, n, Wp, bp);
        pfn_build_kernel<<<(n + 255) / 256, 256, 0, stream>>>(idx, n, head, nxt);
        pfn_output_kernel<<<N_CELLS / 4, 256, 0, stream>>>(x, head, nxt, Wp, bp, out);
    }
}

// Round 12
// 101.957 us; speedup vs baseline: 5.7665x; 1.4513x over previous
//
#include <hip/hip_runtime.h>
#include <hip/hip_fp16.h>

#define N_PY 512
#define IN_F 6
#define OUT_F 64
#define N_CELLS (512 * 512)
#define NCOARSE 256               // coarse bucket = cell >> 10 (1024 cells)
#define NBUCKET 4096              // tile bucket  = cell >> 6   (64 cells)
#define N_SB (NBUCKET * 4)        // (bucket, class) segments = 16384
#define CHUNK 2048                // points per passA block
#define BN_EPS 1e-5

// ---------------------------------------------------------------------------
// ws layout:
//   [0, 108)       : 27 floats — moment accumulators
//   [512, 2304)    : float Wp[64*6], float bp[64] — BN-folded params
//   [4096, 5120)   : int histC[256]  — coarse counts (pristine)
//   [5120, 6144)   : int baseC[256]  — coarse exclusive scan (pristine)
//   [6144, 7168)   : int curC[256]   — mutable cursor for passA
//   [7168, 72708)  : int S[16385]    — fine segment starts (passB) + sentinel
//   [73728, +16n)  : uint4 rec[n]    — coarse-grouped 16B records
//   [73728+16n, +16n): uint4 rec2[n] — fine-sorted records
// All producer/consumer ordering is block-local (no cross-kernel slice
// contracts — the R10 bug class). Every global write is a contiguous run
// (passA, >=128B), a single-owner L2-resident window (passB), or streaming.
// ---------------------------------------------------------------------------

__device__ __forceinline__ unsigned pack2h(float a, float b) {
    __half ha = __float2half_rn(a), hb = __float2half_rn(b);
    unsigned short ua = *reinterpret_cast<unsigned short*>(&ha);
    unsigned short ub = *reinterpret_cast<unsigned short*>(&hb);
    return (unsigned)ua | ((unsigned)ub << 16);
}

__device__ __forceinline__ float2 unpack2h(unsigned u) {
    __half2 h = *reinterpret_cast<__half2*>(&u);
    return __half22float2(h);
}

// ---- 1) moments + coarse histogram (LDS pre-aggregated) ----
__global__ void __launch_bounds__(256)
pfn_stats_hist_kernel(const float* __restrict__ x, const int* __restrict__ idx,
                      int n, float* __restrict__ acc, int* __restrict__ histC) {
    __shared__ int lhist[NCOARSE];
    const int tid = blockIdx.x * blockDim.x + threadIdx.x;
    const int stride = gridDim.x * blockDim.x;
    const int npairs = n >> 1;

    for (int k = threadIdx.x; k < NCOARSE; k += 256) lhist[k] = 0;
    __syncthreads();

    float s[27];
#pragma unroll
    for (int k = 0; k < 27; ++k) s[k] = 0.f;

    for (int q = tid; q < npairs; q += stride) {
        const float4* base4 = (const float4*)(x + (size_t)q * 12);
        const float4 a = base4[0];
        const float4 b4 = base4[1];
        const float4 c4 = base4[2];
        const int4 ij2 = ((const int4*)idx)[q];
        const float p0[6] = {a.x, a.y, a.z, a.w, b4.x, b4.y};
        const float p1[6] = {b4.z, b4.w, c4.x, c4.y, c4.z, c4.w};
#pragma unroll
        for (int j = 0; j < 6; ++j) s[j] += p0[j] + p1[j];
        int k = 6;
#pragma unroll
        for (int i = 0; i < 6; ++i)
#pragma unroll
            for (int j = i; j < 6; ++j) {
                s[k] += p0[i] * p0[j] + p1[i] * p1[j];
                ++k;
            }
        atomicAdd(&lhist[(ij2.x * N_PY + ij2.y) >> 10], 1);
        atomicAdd(&lhist[(ij2.z * N_PY + ij2.w) >> 10], 1);
    }
    if ((n & 1) && tid == 0) {
        const float* p = x + (size_t)(n - 1) * 6;
        float v[6];
#pragma unroll
        for (int j = 0; j < 6; ++j) v[j] = p[j];
#pragma unroll
        for (int j = 0; j < 6; ++j) s[j] += v[j];
        int k = 6;
#pragma unroll
        for (int i = 0; i < 6; ++i)
#pragma unroll
            for (int j = i; j < 6; ++j) { s[k] += v[i] * v[j]; ++k; }
        const int2 ij = ((const int2*)idx)[n - 1];
        atomicAdd(&lhist[(ij.x * N_PY + ij.y) >> 10], 1);
    }

#pragma unroll
    for (int off = 32; off > 0; off >>= 1)
#pragma unroll
        for (int k = 0; k < 27; ++k) s[k] += __shfl_down(s[k], off, 64);

    __shared__ float lds[4][27];
    const int wid = threadIdx.x >> 6;
    const int lane = threadIdx.x & 63;
    if (lane == 0)
#pragma unroll
        for (int k = 0; k < 27; ++k) lds[wid][k] = s[k];
    __syncthreads();

    if (threadIdx.x < 27) {
        const int k = threadIdx.x;
        const float v = lds[0][k] + lds[1][k] + lds[2][k] + lds[3][k];
        atomicAdd(&acc[k], v);
    }
    // one global atomic per coarse counter per block
    atomicAdd(&histC[threadIdx.x], lhist[threadIdx.x]);
}

// ---- 2) coarse scan + BN fold + S sentinel (1 block, 256 threads) ----
__global__ void __launch_bounds__(256)
pfn_scan_finalize_kernel(const int* __restrict__ histC,
                         int* __restrict__ baseC, int* __restrict__ curC,
                         int* __restrict__ S, int n,
                         const float* __restrict__ acc,
                         const float* __restrict__ W,
                         const float* __restrict__ b,
                         const float* __restrict__ gamma,
                         const float* __restrict__ beta,
                         float* __restrict__ Wp, float* __restrict__ bp) {
    const int tid = threadIdx.x;
    const int v = histC[tid];
    __shared__ int sc[256];
    sc[tid] = v;
    __syncthreads();
#pragma unroll
    for (int off = 1; off < 256; off <<= 1) {
        const int add = (tid >= off) ? sc[tid - off] : 0;
        __syncthreads();
        sc[tid] += add;
        __syncthreads();
    }
    const int excl = sc[tid] - v;
    baseC[tid] = excl;
    curC[tid] = excl;
    if (tid == 0) S[N_SB] = n;   // sentinel for tile kernel

    if (tid < 64) {
        const int f = tid;
        double inv_n = 1.0 / (double)n;
        double mx[6];
#pragma unroll
        for (int j = 0; j < 6; ++j) mx[j] = (double)acc[j] * inv_n;
        double C[6][6];
        {
            int k = 0;
            for (int i = 0; i < 6; ++i)
                for (int j = i; j < 6; ++j) {
                    double e = (double)acc[6 + k] * inv_n - mx[i] * mx[j];
                    C[i][j] = e; C[j][i] = e; ++k;
                }
        }
        double w[6];
#pragma unroll
        for (int j = 0; j < 6; ++j) w[j] = (double)W[f * 6 + j];
        double mean_h = (double)b[f];
#pragma unroll
        for (int j = 0; j < 6; ++j) mean_h += w[j] * mx[j];
        double var_h = 0.0;
        for (int i = 0; i < 6; ++i) {
            double tt = 0.0;
            for (int j = 0; j < 6; ++j) tt += C[i][j] * w[j];
            var_h += w[i] * tt;
        }
        double sgn = (double)gamma[f] / sqrt(var_h + BN_EPS);
#pragma unroll
        for (int j = 0; j < 6; ++j) Wp[f * 6 + j] = (float)(w[j] * sgn);
        bp[f] = (float)(((double)b[f] - mean_h) * sgn + (double)beta[f]);
    }
}

// ---- 3) passA: coarse LDS-staged partition, contiguous-run writes ----
// Each block: 2048 points. Records packed in registers, ranked into a 32KB
// LDS stage grouped by coarse bucket, then written out as contiguous runs
// (~8 records = 128B per bucket per block) appended to each coarse region.
__global__ void __launch_bounds__(256)
pfn_passA_kernel(const float* __restrict__ x, const int* __restrict__ idx,
                 int* __restrict__ curC, uint4* __restrict__ rec, int n) {
    __shared__ int lhist[NCOARSE];   // 1 KB
    __shared__ int lbase[NCOARSE];   // 1 KB
    __shared__ int lcur[NCOARSE];    // 1 KB
    __shared__ int gbase[NCOARSE];   // 1 KB
    __shared__ int sc[256];          // 1 KB
    __shared__ uint4 stg[CHUNK];     // 32 KB

    const int tid = threadIdx.x;
    const int chunkStart = blockIdx.x * CHUNK;
    const int chunkCount = min(CHUNK, n - chunkStart);

    lhist[tid] = 0;
    __syncthreads();

    // phase 1: load idx+x, pack records in registers, LDS histogram
    int cellr[8];
    unsigned u0[8], u1[8], u2[8];
#pragma unroll
    for (int r = 0; r < 8; ++r) {
        const int i = r * 256 + tid;
        cellr[r] = -1;
        if (i < chunkCount) {
            const int p = chunkStart + i;
            const int2 ij = ((const int2*)idx)[p];
            const int cell = ij.x * N_PY + ij.y;
            cellr[r] = cell;
            const float2* xp = (const float2*)(x + (size_t)p * 6);
            const float2 a = xp[0], b2 = xp[1], c = xp[2];
            u0[r] = pack2h(a.x, a.y);
            u1[r] = pack2h(b2.x, b2.y);
            u2[r] = pack2h(c.x, c.y);
            atomicAdd(&lhist[cell >> 10], 1);
        }
    }
    __syncthreads();

    // phase 2: local exclusive scan + reserve global ranges
    const int v = lhist[tid];
    sc[tid] = v;
    __syncthreads();
#pragma unroll
    for (int off = 1; off < 256; off <<= 1) {
        const int add = (tid >= off) ? sc[tid - off] : 0;
        __syncthreads();
        sc[tid] += add;
        __syncthreads();
    }
    const int excl = sc[tid] - v;
    lbase[tid] = excl;
    lcur[tid] = excl;
    gbase[tid] = (v > 0) ? atomicAdd(&curC[tid], v) : 0;
    __syncthreads();

    // phase 3: rank records into the coarse-grouped LDS stage
#pragma unroll
    for (int r = 0; r < 8; ++r) {
        const int cell = cellr[r];
        if (cell >= 0) {
            const int slot = atomicAdd(&lcur[cell >> 10], 1);
            stg[slot] = uint4{u0[r], u1[r], u2[r], (unsigned)cell};
        }
    }
    __syncthreads();

    // phase 4: write out in staged order -> contiguous global runs
#pragma unroll
    for (int r = 0; r < 8; ++r) {
        const int slot = r * 256 + tid;
        if (slot < chunkCount) {
            const uint4 q = stg[slot];
            const int bkt = (int)(q.w >> 10);
            const int dst = gbase[bkt] + (slot - lbase[bkt]);
            rec[dst] = q;
        }
    }
}

// ---- 4) passB: fine sort within single-owner coarse windows ----
// Block c owns segment [baseC[c], baseC[c]+histC[c]) of rec. Local 64-key
// histogram -> wave scan -> scatter rec->rec2 within own 62KB window
// (L2-resident, full-line writebacks). Emits S[16384] segment table.
__global__ void __launch_bounds__(256)
pfn_passB_kernel(const uint4* __restrict__ rec, uint4* __restrict__ rec2,
                 const int* __restrict__ baseC, const int* __restrict__ histC,
                 int* __restrict__ S) {
    __shared__ int lh[64];
    __shared__ int lb[64];
    __shared__ int lc[64];
    const int tid = threadIdx.x;
    const int c = blockIdx.x;
    const int segbase = baseC[c];
    const int cnt = histC[c];

    if (tid < 64) lh[tid] = 0;
    __syncthreads();

    // phase 1: fine histogram (fine = ((cell>>6)&15)<<2 | (cell&3))
    for (int i = tid; i < cnt; i += 256) {
        const uint4 q = rec[segbase + i];
        const int fine = (int)((((q.w >> 6) & 15) << 2) | (q.w & 3));
        atomicAdd(&lh[fine], 1);
    }
    __syncthreads();

    // scan 64 entries in wave 0 via shfl; emit S
    if (tid < 64) {
        const int v = lh[tid];
        int incl = v;
#pragma unroll
        for (int off = 1; off < 64; off <<= 1) {
            const int t2 = __shfl_up(incl, off, 64);
            if (tid >= off) incl += t2;
        }
        const int excl = incl - v;
        lb[tid] = excl;
        lc[tid] = excl;
        S[c * 64 + tid] = segbase + excl;   // global sb = c*64 + fine
    }
    __syncthreads();

    // phase 2: scatter into fine order within the block-owned window
    for (int i = tid; i < cnt; i += 256) {
        const uint4 q = rec[segbase + i];
        const int fine = (int)((((q.w >> 6) & 15) << 2) | (q.w & 3));
        const int off = atomicAdd(&lc[fine], 1);
        rec2[segbase + off] = q;
    }
}

// ---- 5) tile: one block per 64-cell bucket, 4 waves (class-exclusive),
// LDS-staged coalesced record loads, plain LDS +=, 16KB coalesced flush ----
__global__ void __launch_bounds__(256)
pfn_tile_kernel(const uint4* __restrict__ rec2, const int* __restrict__ S,
                const float* __restrict__ Wp, const float* __restrict__ bp,
                float* __restrict__ out) {
    __shared__ float tile[64 * OUT_F];    // 16 KB
    __shared__ uint4 stage[4][64];        // 4 KB
    const int tid = threadIdx.x;
    const int lane = tid & 63;
    const int wid = tid >> 6;
    const int bucket = blockIdx.x;

    float4* t4 = (float4*)tile;
#pragma unroll
    for (int i = 0; i < 4; ++i)
        t4[tid + 256 * i] = float4{0.f, 0.f, 0.f, 0.f};

    const float w0 = Wp[lane * 6 + 0];
    const float w1 = Wp[lane * 6 + 1];
    const float w2 = Wp[lane * 6 + 2];
    const float w3 = Wp[lane * 6 + 3];
    const float w4 = Wp[lane * 6 + 4];
    const float w5 = Wp[lane * 6 + 5];
    const float bb = bp[lane];

    __syncthreads();

    const int sb = (bucket << 2) | wid;   // wave w owns cells with (cell&3)==w
    const int r0 = S[sb];
    const int cnt = S[sb + 1] - r0;
    uint4* stg = stage[wid];

    for (int chunk = 0; chunk < cnt; chunk += 64) {
        const int m = min(64, cnt - chunk);
        const uint4* src = rec2 + (size_t)(r0 + chunk);
        if (lane < m) stg[lane] = src[lane];   // coalesced 16B/lane
#pragma unroll 4
        for (int j = 0; j < m; ++j) {
            const uint4 q = stg[j];            // uniform ds_read: broadcast
            const float2 f01 = unpack2h(q.x);
            const float2 f23 = unpack2h(q.y);
            const float2 f45 = unpack2h(q.z);
            float v = bb;
            v = fmaf(w0, f01.x, v); v = fmaf(w1, f01.y, v);
            v = fmaf(w2, f23.x, v); v = fmaf(w3, f23.y, v);
            v = fmaf(w4, f45.x, v); v = fmaf(w5, f45.y, v);
            tile[(((int)q.w & 63) << 6) | lane] += fmaxf(v, 0.f);
        }
    }
    __syncthreads();

    float4* o4 = (float4*)(out + (size_t)bucket * (64 * OUT_F));
#pragma unroll
    for (int i = 0; i < 4; ++i)
        o4[tid + 256 * i] = t4[tid + 256 * i];
}

// ---- fallback (linked-list path, small ws) ----
__global__ void __launch_bounds__(256)
pfn_build_kernel(const int* __restrict__ idx, int n,
                 int* __restrict__ head, int* __restrict__ nxt) {
    const int p = blockIdx.x * blockDim.x + threadIdx.x;
    if (p >= n) return;
    const int2 ij = ((const int2*)idx)[p];
    const int cell = ij.x * N_PY + ij.y;
    nxt[p] = atomicExch(&head[cell], p);
}

__global__ void pfn_finalize_kernel(const float* __restrict__ acc,
                                    const float* __restrict__ W,
                                    const float* __restrict__ b,
                                    const float* __restrict__ gamma,
                                    const float* __restrict__ beta,
                                    int n,
                                    float* __restrict__ Wp,
                                    float* __restrict__ bp) {
    int f = threadIdx.x;
    double inv_n = 1.0 / (double)n;
    double mx[6];
#pragma unroll
    for (int j = 0; j < 6; ++j) mx[j] = (double)acc[j] * inv_n;
    double C[6][6];
    {
        int k = 0;
        for (int i = 0; i < 6; ++i)
            for (int j = i; j < 6; ++j) {
                double e = (double)acc[6 + k] * inv_n - mx[i] * mx[j];
                C[i][j] = e; C[j][i] = e; ++k;
            }
    }
    double w[6];
#pragma unroll
    for (int j = 0; j < 6; ++j) w[j] = (double)W[f * 6 + j];
    double mean_h = (double)b[f];
#pragma unroll
    for (int j = 0; j < 6; ++j) mean_h += w[j] * mx[j];
    double var_h = 0.0;
    for (int i = 0; i < 6; ++i) {
        double t = 0.0;
        for (int j = 0; j < 6; ++j) t += C[i][j] * w[j];
        var_h += w[i] * t;
    }
    double s = (double)gamma[f] / sqrt(var_h + BN_EPS);
#pragma unroll
    for (int j = 0; j < 6; ++j) Wp[f * 6 + j] = (float)(w[j] * s);
    bp[f] = (float)(((double)b[f] - mean_h) * s + (double)beta[f]);
}

__global__ void __launch_bounds__(256)
pfn_output_kernel(const float* __restrict__ x,
                  const int* __restrict__ head,
                  const int* __restrict__ nxt,
                  const float* __restrict__ Wp,
                  const float* __restrict__ bp,
                  float* __restrict__ out) {
    const int lane = threadIdx.x & 63;
    const int cell = __builtin_amdgcn_readfirstlane(
        (int)((blockIdx.x * blockDim.x + threadIdx.x) >> 6));

    const float w0 = Wp[lane * 6 + 0];
    const float w1 = Wp[lane * 6 + 1];
    const float w2 = Wp[lane * 6 + 2];
    const float w3 = Wp[lane * 6 + 3];
    const float w4 = Wp[lane * 6 + 4];
    const float w5 = Wp[lane * 6 + 5];
    const float bb = bp[lane];

    float s = 0.f;
    int p = head[cell];
    while (p >= 0) {
        const float* xp = x + (size_t)p * 6;
        const int pn = nxt[p];
        float v = bb;
        v = fmaf(w0, xp[0], v);
        v = fmaf(w1, xp[1], v);
        v = fmaf(w2, xp[2], v);
        v = fmaf(w3, xp[3], v);
        v = fmaf(w4, xp[4], v);
        v = fmaf(w5, xp[5], v);
        s += fmaxf(v, 0.0f);
        p = pn;
    }
    out[(size_t)cell * OUT_F + lane] = s;
}

extern "C" void kernel_launch(void* const* d_in, const int* in_sizes, int n_in,
                              void* d_out, int out_size, void* d_ws, size_t ws_size,
                              hipStream_t stream) {
    const float* x     = (const float*)d_in[0];
    const int*   idx   = (const int*)d_in[1];
    const float* W     = (const float*)d_in[2];
    const float* b     = (const float*)d_in[3];
    const float* gamma = (const float*)d_in[4];
    const float* beta  = (const float*)d_in[5];
    float* out = (float*)d_out;

    const int n = in_sizes[0] / IN_F;

    float* acc = (float*)d_ws;
    float* Wp  = (float*)((char*)d_ws + 512);
    float* bp  = Wp + OUT_F * IN_F;

    int*   histC = (int*)((char*)d_ws + 4096);
    int*   baseC = (int*)((char*)d_ws + 5120);
    int*   curC  = (int*)((char*)d_ws + 6144);
    int*   S     = (int*)((char*)d_ws + 7168);    // 16385 ints
    uint4* rec   = (uint4*)((char*)d_ws + 73728);
    uint4* rec2  = rec + n;

    const size_t need = 73728 + (size_t)n * 32;

    if (ws_size >= need) {
        // zero acc + histC (5 KB; everything else fully rewritten per call)
        hipMemsetAsync(d_ws, 0, 5120, stream);
        pfn_stats_hist_kernel<<<1024, 256, 0, stream>>>(x, idx, n, acc, histC);
        pfn_scan_finalize_kernel<<<1, 256, 0, stream>>>(
            histC, baseC, curC, S, n, acc, W, b, gamma, beta, Wp, bp);
        pfn_passA_kernel<<<(n + CHUNK - 1) / CHUNK, 256, 0, stream>>>(
            x, idx, curC, rec, n);
        pfn_passB_kernel<<<NCOARSE, 256, 0, stream>>>(rec, rec2, baseC, histC, S);
        pfn_tile_kernel<<<NBUCKET, 256, 0, stream>>>(rec2, S, Wp, bp, out);
    } else {
        // linked-list fallback
        int* head = (int*)((char*)d_ws + 4096);
        int* nxt  = head + N_CELLS;
        hipMemsetAsync(d_ws, 0, 5120, stream);
        pfn_stats_hist_kernel<<<1024, 256, 0, stream>>>(x, idx, n, acc, histC);
        hipMemsetAsync(head, 0xFF, (size_t)N_CELLS * sizeof(int), stream);
        pfn_finalize_kernel<<<1, 64, 0, stream>>>(acc, W, b, gamma, beta, n, Wp, bp);
        pfn_build_kernel<<<(n + 255) / 256, 256, 0, stream>>>(idx, n, head, nxt);
        pfn_output_kernel<<<N_CELLS / 4, 256, 0, stream>>>(x, head, nxt, Wp, bp, out);
    }
}

// Round 13
// 85.586 us; speedup vs baseline: 6.8695x; 1.1913x over previous
//
#include <hip/hip_runtime.h>
#include <hip/hip_fp16.h>

#define N_PY 512
#define IN_F 6
#define OUT_F 64
#define N_CELLS (512 * 512)
#define NCOARSE 256               // coarse bucket = cell >> 10 (1024 cells)
#define NBUCKET 4096              // tile bucket  = cell >> 6   (64 cells)
#define N_SB (NBUCKET * 4)        // (bucket, class) segments = 16384
#define CHUNK 2048                // points per passA block
#define BN_EPS 1e-5

// ---------------------------------------------------------------------------
// ws layout:
//   [0, 108)       : 27 floats — moment accumulators (written by passA)
//   [512, 2304)    : float Wp[64*6], float bp[64] — BN-folded params (passB)
//   [4096, 5120)   : int histC[256]  — coarse counts (pristine)
//   [5120, 6144)   : int baseC[256]  — coarse exclusive scan (pristine)
//   [6144, 7168)   : int curC[256]   — mutable cursor for passA
//   [7168, 72708)  : int S[16385]    — fine segment starts (passB) + sentinel
//   [73728, +16n)  : uint4 rec[n]    — coarse-grouped 16B records
//   [73728+16n, +16n): uint4 rec2[n] — fine-sorted records
// Pipeline: memset(5KB) -> hist(idx only) -> scan -> passA(x+idx, moments,
// grouped-run writes) -> passB(fine sort in single-owner windows + BN fold)
// -> tile (class-exclusive LDS accumulate, coalesced flush).
// ---------------------------------------------------------------------------

__device__ __forceinline__ unsigned pack2h(float a, float b) {
    __half ha = __float2half_rn(a), hb = __float2half_rn(b);
    unsigned short ua = *reinterpret_cast<unsigned short*>(&ha);
    unsigned short ub = *reinterpret_cast<unsigned short*>(&hb);
    return (unsigned)ua | ((unsigned)ub << 16);
}

__device__ __forceinline__ float2 unpack2h(unsigned u) {
    __half2 h = *reinterpret_cast<__half2*>(&u);
    return __half22float2(h);
}

// ---- 1) coarse histogram from idx only (LDS pre-aggregated) ----
__global__ void __launch_bounds__(256)
pfn_hist_kernel(const int* __restrict__ idx, int n, int* __restrict__ histC) {
    __shared__ int lhist[NCOARSE];
    const int tid = blockIdx.x * blockDim.x + threadIdx.x;
    const int stride = gridDim.x * blockDim.x;
    const int npairs = n >> 1;

    lhist[threadIdx.x] = 0;
    __syncthreads();

    for (int q = tid; q < npairs; q += stride) {
        const int4 ij2 = ((const int4*)idx)[q];
        atomicAdd(&lhist[(ij2.x * N_PY + ij2.y) >> 10], 1);
        atomicAdd(&lhist[(ij2.z * N_PY + ij2.w) >> 10], 1);
    }
    if ((n & 1) && tid == 0) {
        const int2 ij = ((const int2*)idx)[n - 1];
        atomicAdd(&lhist[(ij.x * N_PY + ij.y) >> 10], 1);
    }
    __syncthreads();
    atomicAdd(&histC[threadIdx.x], lhist[threadIdx.x]);
}

// ---- 2) coarse scan + S sentinel (1 block, 256 threads) ----
__global__ void __launch_bounds__(256)
pfn_scan_kernel(const int* __restrict__ histC,
                int* __restrict__ baseC, int* __restrict__ curC,
                int* __restrict__ S, int n) {
    const int tid = threadIdx.x;
    const int v = histC[tid];
    __shared__ int sc[256];
    sc[tid] = v;
    __syncthreads();
#pragma unroll
    for (int off = 1; off < 256; off <<= 1) {
        const int add = (tid >= off) ? sc[tid - off] : 0;
        __syncthreads();
        sc[tid] += add;
        __syncthreads();
    }
    const int excl = sc[tid] - v;
    baseC[tid] = excl;
    curC[tid] = excl;
    if (tid == 0) S[N_SB] = n;   // sentinel for tile kernel
}

// ---- 3) passA: coarse LDS-staged partition + moment accumulation ----
// Each block: 2048 points. Records packed in registers, ranked into a 32KB
// LDS stage grouped by coarse bucket, written out as contiguous runs
// (~8 records = 128B per bucket per block). Moments accumulated on the
// exact f32 values already in registers (x is read ONCE total now).
__global__ void __launch_bounds__(256)
pfn_passA_kernel(const float* __restrict__ x, const int* __restrict__ idx,
                 int* __restrict__ curC, uint4* __restrict__ rec,
                 float* __restrict__ acc, int n) {
    __shared__ int lhist[NCOARSE];   // 1 KB
    __shared__ int lbase[NCOARSE];   // 1 KB
    __shared__ int lcur[NCOARSE];    // 1 KB
    __shared__ int gbase[NCOARSE];   // 1 KB
    __shared__ int sc[256];          // 1 KB
    __shared__ uint4 stg[CHUNK];     // 32 KB
    __shared__ float lmom[4][27];

    const int tid = threadIdx.x;
    const int chunkStart = blockIdx.x * CHUNK;
    const int chunkCount = min(CHUNK, n - chunkStart);

    lhist[tid] = 0;
    __syncthreads();

    float s[27];
#pragma unroll
    for (int k = 0; k < 27; ++k) s[k] = 0.f;

    // phase 1: load idx+x, moments, pack records, LDS histogram
    int cellr[8];
    unsigned u0[8], u1[8], u2[8];
#pragma unroll
    for (int r = 0; r < 8; ++r) {
        const int i = r * 256 + tid;
        cellr[r] = -1;
        if (i < chunkCount) {
            const int p = chunkStart + i;
            const int2 ij = ((const int2*)idx)[p];
            const int cell = ij.x * N_PY + ij.y;
            cellr[r] = cell;
            const float2* xp = (const float2*)(x + (size_t)p * 6);
            const float2 a = xp[0], b2 = xp[1], c = xp[2];
            const float v6[6] = {a.x, a.y, b2.x, b2.y, c.x, c.y};
#pragma unroll
            for (int j = 0; j < 6; ++j) s[j] += v6[j];
            int k = 6;
#pragma unroll
            for (int i2 = 0; i2 < 6; ++i2)
#pragma unroll
                for (int j = i2; j < 6; ++j) { s[k] += v6[i2] * v6[j]; ++k; }
            u0[r] = pack2h(a.x, a.y);
            u1[r] = pack2h(b2.x, b2.y);
            u2[r] = pack2h(c.x, c.y);
            atomicAdd(&lhist[cell >> 10], 1);
        }
    }
    __syncthreads();

    // phase 2: local exclusive scan + reserve global ranges
    const int v = lhist[tid];
    sc[tid] = v;
    __syncthreads();
#pragma unroll
    for (int off = 1; off < 256; off <<= 1) {
        const int add = (tid >= off) ? sc[tid - off] : 0;
        __syncthreads();
        sc[tid] += add;
        __syncthreads();
    }
    const int excl = sc[tid] - v;
    lbase[tid] = excl;
    lcur[tid] = excl;
    gbase[tid] = (v > 0) ? atomicAdd(&curC[tid], v) : 0;
    __syncthreads();

    // phase 3: rank records into the coarse-grouped LDS stage
#pragma unroll
    for (int r = 0; r < 8; ++r) {
        const int cell = cellr[r];
        if (cell >= 0) {
            const int slot = atomicAdd(&lcur[cell >> 10], 1);
            stg[slot] = uint4{u0[r], u1[r], u2[r], (unsigned)cell};
        }
    }
    __syncthreads();

    // phase 4: write out in staged order -> contiguous global runs
#pragma unroll
    for (int r = 0; r < 8; ++r) {
        const int slot = r * 256 + tid;
        if (slot < chunkCount) {
            const uint4 q = stg[slot];
            const int bkt = (int)(q.w >> 10);
            const int dst = gbase[bkt] + (slot - lbase[bkt]);
            rec[dst] = q;
        }
    }

    // moments: wave reduce -> cross-wave LDS -> 27 global atomics per block
#pragma unroll
    for (int off = 32; off > 0; off >>= 1)
#pragma unroll
        for (int k = 0; k < 27; ++k) s[k] += __shfl_down(s[k], off, 64);
    const int wid = tid >> 6;
    const int lane = tid & 63;
    if (lane == 0)
#pragma unroll
        for (int k = 0; k < 27; ++k) lmom[wid][k] = s[k];
    __syncthreads();
    if (tid < 27) {
        const int k = tid;
        atomicAdd(&acc[k], lmom[0][k] + lmom[1][k] + lmom[2][k] + lmom[3][k]);
    }
}

// ---- 4) passB: fine sort within single-owner coarse windows + BN fold ----
__global__ void __launch_bounds__(256)
pfn_passB_kernel(const uint4* __restrict__ rec, uint4* __restrict__ rec2,
                 const int* __restrict__ baseC, const int* __restrict__ histC,
                 int* __restrict__ S, int n,
                 const float* __restrict__ acc,
                 const float* __restrict__ W,
                 const float* __restrict__ b,
                 const float* __restrict__ gamma,
                 const float* __restrict__ beta,
                 float* __restrict__ Wp, float* __restrict__ bp) {
    __shared__ int lh[64];
    __shared__ int lc[64];
    const int tid = threadIdx.x;
    const int c = blockIdx.x;
    const int segbase = baseC[c];
    const int cnt = histC[c];

    if (tid < 64) lh[tid] = 0;
    __syncthreads();

    // BN fold on block 0 lanes 0..63 (acc complete: passA finished).
    // Straight-line, no barriers inside -> other waves proceed to hist loop.
    if (c == 0 && tid < 64) {
        const int f = tid;
        double inv_n = 1.0 / (double)n;
        double mx[6];
#pragma unroll
        for (int j = 0; j < 6; ++j) mx[j] = (double)acc[j] * inv_n;
        double C[6][6];
        {
            int k = 0;
            for (int i = 0; i < 6; ++i)
                for (int j = i; j < 6; ++j) {
                    double e = (double)acc[6 + k] * inv_n - mx[i] * mx[j];
                    C[i][j] = e; C[j][i] = e; ++k;
                }
        }
        double w[6];
#pragma unroll
        for (int j = 0; j < 6; ++j) w[j] = (double)W[f * 6 + j];
        double mean_h = (double)b[f];
#pragma unroll
        for (int j = 0; j < 6; ++j) mean_h += w[j] * mx[j];
        double var_h = 0.0;
        for (int i = 0; i < 6; ++i) {
            double tt = 0.0;
            for (int j = 0; j < 6; ++j) tt += C[i][j] * w[j];
            var_h += w[i] * tt;
        }
        double sgn = (double)gamma[f] / sqrt(var_h + BN_EPS);
#pragma unroll
        for (int j = 0; j < 6; ++j) Wp[f * 6 + j] = (float)(w[j] * sgn);
        bp[f] = (float)(((double)b[f] - mean_h) * sgn + (double)beta[f]);
    }

    // phase 1: fine histogram (fine = ((cell>>6)&15)<<2 | (cell&3))
    for (int i = tid; i < cnt; i += 256) {
        const uint4 q = rec[segbase + i];
        const int fine = (int)((((q.w >> 6) & 15) << 2) | (q.w & 3));
        atomicAdd(&lh[fine], 1);
    }
    __syncthreads();

    // scan 64 entries in wave 0 via shfl; emit S
    if (tid < 64) {
        const int v = lh[tid];
        int incl = v;
#pragma unroll
        for (int off = 1; off < 64; off <<= 1) {
            const int t2 = __shfl_up(incl, off, 64);
            if (tid >= off) incl += t2;
        }
        const int excl = incl - v;
        lc[tid] = excl;
        S[c * 64 + tid] = segbase + excl;   // global sb = c*64 + fine
    }
    __syncthreads();

    // phase 2: scatter into fine order within the block-owned window
    for (int i = tid; i < cnt; i += 256) {
        const uint4 q = rec[segbase + i];
        const int fine = (int)((((q.w >> 6) & 15) << 2) | (q.w & 3));
        const int off = atomicAdd(&lc[fine], 1);
        rec2[segbase + off] = q;
    }
}

// ---- 5) tile: one block per 64-cell bucket, 4 waves (class-exclusive),
// LDS-staged coalesced record loads, plain LDS +=, 16KB coalesced flush ----
__global__ void __launch_bounds__(256)
pfn_tile_kernel(const uint4* __restrict__ rec2, const int* __restrict__ S,
                const float* __restrict__ Wp, const float* __restrict__ bp,
                float* __restrict__ out) {
    __shared__ float tile[64 * OUT_F];    // 16 KB
    __shared__ uint4 stage[4][64];        // 4 KB
    const int tid = threadIdx.x;
    const int lane = tid & 63;
    const int wid = tid >> 6;
    const int bucket = blockIdx.x;

    float4* t4 = (float4*)tile;
#pragma unroll
    for (int i = 0; i < 4; ++i)
        t4[tid + 256 * i] = float4{0.f, 0.f, 0.f, 0.f};

    const float w0 = Wp[lane * 6 + 0];
    const float w1 = Wp[lane * 6 + 1];
    const float w2 = Wp[lane * 6 + 2];
    const float w3 = Wp[lane * 6 + 3];
    const float w4 = Wp[lane * 6 + 4];
    const float w5 = Wp[lane * 6 + 5];
    const float bb = bp[lane];

    __syncthreads();

    const int sb = (bucket << 2) | wid;   // wave w owns cells with (cell&3)==w
    const int r0 = S[sb];
    const int cnt = S[sb + 1] - r0;
    uint4* stg = stage[wid];

    for (int chunk = 0; chunk < cnt; chunk += 64) {
        const int m = min(64, cnt - chunk);
        const uint4* src = rec2 + (size_t)(r0 + chunk);
        if (lane < m) stg[lane] = src[lane];   // coalesced 16B/lane
#pragma unroll 4
        for (int j = 0; j < m; ++j) {
            const uint4 q = stg[j];            // uniform ds_read: broadcast
            const float2 f01 = unpack2h(q.x);
            const float2 f23 = unpack2h(q.y);
            const float2 f45 = unpack2h(q.z);
            float v = bb;
            v = fmaf(w0, f01.x, v); v = fmaf(w1, f01.y, v);
            v = fmaf(w2, f23.x, v); v = fmaf(w3, f23.y, v);
            v = fmaf(w4, f45.x, v); v = fmaf(w5, f45.y, v);
            tile[(((int)q.w & 63) << 6) | lane] += fmaxf(v, 0.f);
        }
    }
    __syncthreads();

    float4* o4 = (float4*)(out + (size_t)bucket * (64 * OUT_F));
#pragma unroll
    for (int i = 0; i < 4; ++i)
        o4[tid + 256 * i] = t4[tid + 256 * i];
}

// ---- fallback (linked-list path, small ws) ----
__global__ void __launch_bounds__(256)
pfn_moments_kernel(const float* __restrict__ x, int n, float* __restrict__ acc) {
    const int tid = blockIdx.x * blockDim.x + threadIdx.x;
    const int stride = gridDim.x * blockDim.x;
    const int npairs = n >> 1;

    float s[27];
#pragma unroll
    for (int k = 0; k < 27; ++k) s[k] = 0.f;

    for (int q = tid; q < npairs; q += stride) {
        const float4* base4 = (const float4*)(x + (size_t)q * 12);
        const float4 a = base4[0];
        const float4 b4 = base4[1];
        const float4 c4 = base4[2];
        const float p0[6] = {a.x, a.y, a.z, a.w, b4.x, b4.y};
        const float p1[6] = {b4.z, b4.w, c4.x, c4.y, c4.z, c4.w};
#pragma unroll
        for (int j = 0; j < 6; ++j) s[j] += p0[j] + p1[j];
        int k = 6;
#pragma unroll
        for (int i = 0; i < 6; ++i)
#pragma unroll
            for (int j = i; j < 6; ++j) {
                s[k] += p0[i] * p0[j] + p1[i] * p1[j];
                ++k;
            }
    }
    if ((n & 1) && tid == 0) {
        const float* p = x + (size_t)(n - 1) * 6;
        float v[6];
#pragma unroll
        for (int j = 0; j < 6; ++j) v[j] = p[j];
#pragma unroll
        for (int j = 0; j < 6; ++j) s[j] += v[j];
        int k = 6;
#pragma unroll
        for (int i = 0; i < 6; ++i)
#pragma unroll
            for (int j = i; j < 6; ++j) { s[k] += v[i] * v[j]; ++k; }
    }

#pragma unroll
    for (int off = 32; off > 0; off >>= 1)
#pragma unroll
        for (int k = 0; k < 27; ++k) s[k] += __shfl_down(s[k], off, 64);

    __shared__ float lds[4][27];
    const int wid = threadIdx.x >> 6;
    const int lane = threadIdx.x & 63;
    if (lane == 0)
#pragma unroll
        for (int k = 0; k < 27; ++k) lds[wid][k] = s[k];
    __syncthreads();

    if (threadIdx.x < 27) {
        const int k = threadIdx.x;
        atomicAdd(&acc[k], lds[0][k] + lds[1][k] + lds[2][k] + lds[3][k]);
    }
}

__global__ void pfn_finalize_kernel(const float* __restrict__ acc,
                                    const float* __restrict__ W,
                                    const float* __restrict__ b,
                                    const float* __restrict__ gamma,
                                    const float* __restrict__ beta,
                                    int n,
                                    float* __restrict__ Wp,
                                    float* __restrict__ bp) {
    int f = threadIdx.x;
    double inv_n = 1.0 / (double)n;
    double mx[6];
#pragma unroll
    for (int j = 0; j < 6; ++j) mx[j] = (double)acc[j] * inv_n;
    double C[6][6];
    {
        int k = 0;
        for (int i = 0; i < 6; ++i)
            for (int j = i; j < 6; ++j) {
                double e = (double)acc[6 + k] * inv_n - mx[i] * mx[j];
                C[i][j] = e; C[j][i] = e; ++k;
            }
    }
    double w[6];
#pragma unroll
    for (int j = 0; j < 6; ++j) w[j] = (double)W[f * 6 + j];
    double mean_h = (double)b[f];
#pragma unroll
    for (int j = 0; j < 6; ++j) mean_h += w[j] * mx[j];
    double var_h = 0.0;
    for (int i = 0; i < 6; ++i) {
        double t = 0.0;
        for (int j = 0; j < 6; ++j) t += C[i][j] * w[j];
        var_h += w[i] * t;
    }
    double s = (double)gamma[f] / sqrt(var_h + BN_EPS);
#pragma unroll
    for (int j = 0; j < 6; ++j) Wp[f * 6 + j] = (float)(w[j] * s);
    bp[f] = (float)(((double)b[f] - mean_h) * s + (double)beta[f]);
}

__global__ void __launch_bounds__(256)
pfn_build_kernel(const int* __restrict__ idx, int n,
                 int* __restrict__ head, int* __restrict__ nxt) {
    const int p = blockIdx.x * blockDim.x + threadIdx.x;
    if (p >= n) return;
    const int2 ij = ((const int2*)idx)[p];
    const int cell = ij.x * N_PY + ij.y;
    nxt[p] = atomicExch(&head[cell], p);
}

__global__ void __launch_bounds__(256)
pfn_output_kernel(const float* __restrict__ x,
                  const int* __restrict__ head,
                  const int* __restrict__ nxt,
                  const float* __restrict__ Wp,
                  const float* __restrict__ bp,
                  float* __restrict__ out) {
    const int lane = threadIdx.x & 63;
    const int cell = __builtin_amdgcn_readfirstlane(
        (int)((blockIdx.x * blockDim.x + threadIdx.x) >> 6));

    const float w0 = Wp[lane * 6 + 0];
    const float w1 = Wp[lane * 6 + 1];
    const float w2 = Wp[lane * 6 + 2];
    const float w3 = Wp[lane * 6 + 3];
    const float w4 = Wp[lane * 6 + 4];
    const float w5 = Wp[lane * 6 + 5];
    const float bb = bp[lane];

    float s = 0.f;
    int p = head[cell];
    while (p >= 0) {
        const float* xp = x + (size_t)p * 6;
        const int pn = nxt[p];
        float v = bb;
        v = fmaf(w0, xp[0], v);
        v = fmaf(w1, xp[1], v);
        v = fmaf(w2, xp[2], v);
        v = fmaf(w3, xp[3], v);
        v = fmaf(w4, xp[4], v);
        v = fmaf(w5, xp[5], v);
        s += fmaxf(v, 0.0f);
        p = pn;
    }
    out[(size_t)cell * OUT_F + lane] = s;
}

extern "C" void kernel_launch(void* const* d_in, const int* in_sizes, int n_in,
                              void* d_out, int out_size, void* d_ws, size_t ws_size,
                              hipStream_t stream) {
    const float* x     = (const float*)d_in[0];
    const int*   idx   = (const int*)d_in[1];
    const float* W     = (const float*)d_in[2];
    const float* b     = (const float*)d_in[3];
    const float* gamma = (const float*)d_in[4];
    const float* beta  = (const float*)d_in[5];
    float* out = (float*)d_out;

    const int n = in_sizes[0] / IN_F;

    float* acc = (float*)d_ws;
    float* Wp  = (float*)((char*)d_ws + 512);
    float* bp  = Wp + OUT_F * IN_F;

    int*   histC = (int*)((char*)d_ws + 4096);
    int*   baseC = (int*)((char*)d_ws + 5120);
    int*   curC  = (int*)((char*)d_ws + 6144);
    int*   S     = (int*)((char*)d_ws + 7168);    // 16385 ints
    uint4* rec   = (uint4*)((char*)d_ws + 73728);
    uint4* rec2  = rec + n;

    const size_t need = 73728 + (size_t)n * 32;

    if (ws_size >= need) {
        // zero acc + histC (5 KB; everything else fully rewritten per call)
        hipMemsetAsync(d_ws, 0, 5120, stream);
        pfn_hist_kernel<<<256, 256, 0, stream>>>(idx, n, histC);
        pfn_scan_kernel<<<1, 256, 0, stream>>>(histC, baseC, curC, S, n);
        pfn_passA_kernel<<<(n + CHUNK - 1) / CHUNK, 256, 0, stream>>>(
            x, idx, curC, rec, acc, n);
        pfn_passB_kernel<<<NCOARSE, 256, 0, stream>>>(
            rec, rec2, baseC, histC, S, n, acc, W, b, gamma, beta, Wp, bp);
        pfn_tile_kernel<<<NBUCKET, 256, 0, stream>>>(rec2, S, Wp, bp, out);
    } else {
        // linked-list fallback
        int* head = (int*)((char*)d_ws + 4096);
        int* nxt  = head + N_CELLS;
        hipMemsetAsync(d_ws, 0, 512, stream);
        pfn_moments_kernel<<<1024, 256, 0, stream>>>(x, n, acc);
        hipMemsetAsync(head, 0xFF, (size_t)N_CELLS * sizeof(int), stream);
        pfn_finalize_kernel<<<1, 64, 0, stream>>>(acc, W, b, gamma, beta, n, Wp, bp);
        pfn_build_kernel<<<(n + 255) / 256, 256, 0, stream>>>(idx, n, head, nxt);
        pfn_output_kernel<<<N_CELLS / 4, 256, 0, stream>>>(x, head, nxt, Wp, bp, out);
    }
}